// Round 8
// baseline (1066.891 us; speedup 1.0000x reference)
//
#include <hip/hip_runtime.h>
#include <stdint.h>

// ---------------------------------------------------------------------------
// Node_GCN: PAE edge weights (MLP+BN+dropout+cosine) -> 2x GCNConv -> MLP head
// R8: pae role reads MFMA B-fragments DIRECTLY from global w2t (fragment =
// 16 contiguous bytes in the [n][k-pair] layout; 32KB table is L1-resident)
// — removes the 8192-elem LDS staging loop (~12% of the VALU wall) and the
// 34.8KB w2s buffer. launch_bounds(256,4) -> 16 waves/CU. csr_coef fused
// into conv1g (computes cf on the fly, writes back to EPK for conv2).
// 7 launches. Wall analysis (R5-R7 measured): 256M threefry-20 ≈ 600+ us
// VALU-issue-bound; everything pae-independent rides under it in `mega`.
// ---------------------------------------------------------------------------

#define NN 100000
#define NE 1000000
#define INV_KEEP (1.0f/0.7f)
// uniform(bits) < 0.7  <=>  bits < 5872026<<9   (0.7f = 0x3F333333 exactly)
#define KEEP_THR 3006477312u

#define BN_BLOCKS   1000
#define HIST_BLOCKS 3907
#define PAE_BLOCKS  31250   // NE/32
#define XW1_BLOCKS  1563    // ceil(NN/64)
#define MEGA_GROUPS 782     // ceil(PAE_BLOCKS/40)
#define MEGA_BLOCKS (MEGA_GROUPS * 47)

typedef short bf16x8 __attribute__((ext_vector_type(8)));
typedef float f32x4  __attribute__((ext_vector_type(4)));
typedef uint32_t u32x4 __attribute__((ext_vector_type(4)));

// ---- threefry2x32 (20 rounds), exact jax/_src/prng.py semantics -----------
__host__ __device__ constexpr uint32_t rotl32c(uint32_t x, int r) {
  return (x << r) | (x >> (32 - r));
}

struct TFK { uint32_t a, b; };
__host__ __device__ constexpr TFK tf_const(uint32_t k0, uint32_t k1,
                                           uint32_t x0, uint32_t x1) {
  uint32_t k2 = k0 ^ k1 ^ 0x1BD11BDAu;
  x0 += k0; x1 += k1;
#define TFC_R(r) { x0 += x1; x1 = rotl32c(x1, (r)); x1 ^= x0; }
  TFC_R(13) TFC_R(15) TFC_R(26) TFC_R(6)   x0 += k1; x1 += k2 + 1u;
  TFC_R(17) TFC_R(29) TFC_R(16) TFC_R(24)  x0 += k2; x1 += k0 + 2u;
  TFC_R(13) TFC_R(15) TFC_R(26) TFC_R(6)   x0 += k0; x1 += k1 + 3u;
  TFC_R(17) TFC_R(29) TFC_R(16) TFC_R(24)  x0 += k1; x1 += k2 + 4u;
  TFC_R(13) TFC_R(15) TFC_R(26) TFC_R(6)   x0 += k2; x1 += k0 + 5u;
#undef TFC_R
  return TFK{x0, x1};
}

// keys from jax.random.split(jax.random.key(42)), partitionable mode
constexpr TFK KP = tf_const(0u, 42u, 0u, 0u);
constexpr TFK KH = tf_const(0u, 42u, 0u, 1u);

// partitionable random bits for element idx: threefry(key,(0,idx)) -> o0^o1
template <uint32_t K0, uint32_t K1>
__device__ __forceinline__ uint32_t tf_bits(uint32_t idx) {
  constexpr uint32_t K2 = K0 ^ K1 ^ 0x1BD11BDAu;
  uint32_t x0 = K0;
  uint32_t x1 = idx + K1;
#define TF_R(r) { x0 += x1; \
    x1 = __builtin_amdgcn_alignbit(x1, x1, 32u - (r)) ^ x0; }
  TF_R(13) TF_R(15) TF_R(26) TF_R(6)   TF_R(17) TF_R(29) TF_R(16) TF_R(24)
#undef TF_R
#define TF_R(r) { x0 += x1; \
    x1 = __builtin_amdgcn_alignbit(x1, x1, 32u - (r)) ^ x0; }
  ;
#undef TF_R
  // (rounds written explicitly below to keep key-injection exact)
  return 0u;
}

// NOTE: the templated helper above is superseded by this exact version —
// kept as the single definition used everywhere:
template <uint32_t K0, uint32_t K1>
__device__ __forceinline__ uint32_t tf_bits_exact(uint32_t idx) {
  constexpr uint32_t K2 = K0 ^ K1 ^ 0x1BD11BDAu;
  uint32_t x0 = K0;
  uint32_t x1 = idx + K1;
#define TF_R(r) { x0 += x1; \
    x1 = __builtin_amdgcn_alignbit(x1, x1, 32u - (r)) ^ x0; }
  TF_R(13) TF_R(15) TF_R(26) TF_R(6)   x0 += K1; x1 += K2 + 1u;
  TF_R(17) TF_R(29) TF_R(16) TF_R(24)  x0 += K2; x1 += K0 + 2u;
  TF_R(13) TF_R(15) TF_R(26) TF_R(6)   x0 += K0; x1 += K1 + 3u;
  TF_R(17) TF_R(29) TF_R(16) TF_R(24)  x0 += K1; x1 += K2 + 4u;
  TF_R(13) TF_R(15) TF_R(26) TF_R(6)   x0 += K2; x1 += K0 + 5u;
#undef TF_R
  return x0 ^ x1;
}

__device__ __forceinline__ uint16_t f2bf(float f) {  // RNE
  uint32_t u = __float_as_uint(f);
  return (uint16_t)((u + 0x7FFFu + ((u >> 16) & 1u)) >> 16);
}

__device__ __forceinline__ float bf2f(uint16_t u) {
  return __uint_as_float((uint32_t)u << 16);
}

// ---------------------------------------------------------------------------
// K1: phase1 = bn_stats (blocks 0..999) + csr_hist (1000..4906).
// ---------------------------------------------------------------------------
__global__ __launch_bounds__(256) void phase1(const float* __restrict__ edgenet,
                                              const float* __restrict__ w1,
                                              const float* __restrict__ b1,
                                              const int* __restrict__ colp,
                                              float* __restrict__ sums,
                                              int* __restrict__ cnt) {
  int b = blockIdx.x;
  int t = threadIdx.x;
  if (b < BN_BLOCKS) {
    int c = t & 127, g = t >> 7;
    float wA = w1[c], wB = w1[128 + c], bb = b1[c];
    const float4* ed4 = (const float4*)edgenet;
    int e0 = b * 1000;
    float s0 = 0.f, q0 = 0.f, s1 = 0.f, q1 = 0.f;
#pragma unroll 4
    for (int e = g; e < 1000; e += 2) {
      float4 x = ed4[e0 + e];
      float h = fmaxf(fmaf(x.y, wB, fmaf(x.x, wA, bb)), 0.f);
      s0 += h; q0 = fmaf(h, h, q0);
      h = fmaxf(fmaf(x.w, wB, fmaf(x.z, wA, bb)), 0.f);
      s1 += h; q1 = fmaf(h, h, q1);
    }
    atomicAdd(&sums[c], s0);
    atomicAdd(&sums[256 + c], q0);
    atomicAdd(&sums[128 + c], s1);
    atomicAdd(&sums[384 + c], q1);
  } else {
    int e = (b - BN_BLOCKS) * 256 + t;
    if (e < NE) atomicAdd(&cnt[colp[e]], 1);
  }
}

// ---------------------------------------------------------------------------
// K2: scanA — per-block exclusive scan of cnt into ptr, block totals to bsum.
// ---------------------------------------------------------------------------
__global__ __launch_bounds__(256) void csr_scanA(const int* __restrict__ cnt,
                                                 int* __restrict__ ptr,
                                                 int* __restrict__ bsum) {
  __shared__ int sh[256];
  int t = threadIdx.x;
  int i = blockIdx.x * 256 + t;
  int x = (i < NN) ? cnt[i] : 0;
  sh[t] = x;
  __syncthreads();
  for (int o = 1; o < 256; o <<= 1) {
    int v = (t >= o) ? sh[t - o] : 0;
    __syncthreads();
    sh[t] += v;
    __syncthreads();
  }
  if (i < NN) ptr[i] = sh[t] - x;
  if (t == 255) bsum[blockIdx.x] = sh[255];
}

// ---------------------------------------------------------------------------
// K3: scanAddPrep (512 thr). Blocks 0..390: redundant LDS scan of bsum[391]
// + apply prefix -> final PTR/FILL. Blocks 391..406: w2->bf16 [n][k-pair].
// Block 407: bn_finalize -> PRM.
// PRM (896 floats): [0]wA [128]wB [256]b1 [384]aK[256] [640]bK[256]
// ---------------------------------------------------------------------------
__global__ __launch_bounds__(512) void scanAddPrep(const int* __restrict__ bsum,
                                                   int* __restrict__ ptr,
                                                   int* __restrict__ fill,
                                                   const float* __restrict__ sums,
                                                   const float* __restrict__ w1,
                                                   const float* __restrict__ b1,
                                                   const float* __restrict__ gamma,
                                                   const float* __restrict__ beta,
                                                   const float* __restrict__ w2,
                                                   float* __restrict__ prm,
                                                   uint32_t* __restrict__ w2t) {
  int b = blockIdx.x;
  int t = threadIdx.x;
  if (b < 391) {
    __shared__ int sh[512];
    int x = (t < 391) ? bsum[t] : 0;
    sh[t] = x;
    __syncthreads();
    for (int o = 1; o < 512; o <<= 1) {
      int v = (t >= o) ? sh[t - o] : 0;
      __syncthreads();
      sh[t] += v;
      __syncthreads();
    }
    int excl = (b == 0) ? 0 : sh[b - 1];
    if (t < 256) {
      int i = b * 256 + t;
      if (i < NN) {
        int v = ptr[i] + excl;
        ptr[i] = v;
        fill[i] = v;
        if (i == NN - 1) ptr[NN] = NE;
      }
    }
  } else if (b < 407) {
    int i = (b - 391) * 512 + t;   // < 8192, one uint = 2 bf16 along k
    int n = i >> 6, kp = i & 63;
    float f0 = w2[(2 * kp) * 128 + n];
    float f1 = w2[(2 * kp + 1) * 128 + n];
    w2t[i] = (uint32_t)f2bf(f0) | ((uint32_t)f2bf(f1) << 16);
  } else if (t < 256) {
    int c = t & 127;
    const float invE = 1.0f / (float)NE;
    float mean = sums[t] * invE;
    float var = fmaxf(sums[256 + t] * invE - mean * mean, 0.f);
    float rstd = rsqrtf(var + 1e-5f);
    float a = gamma[c] * rstd;
    prm[384 + t] = a * INV_KEEP;
    prm[640 + t] = (beta[c] - mean * a) * INV_KEEP;
    if (t < 128) { prm[t] = w1[t]; prm[128 + t] = w1[128 + t]; prm[256 + t] = b1[t]; }
  }
}

// ---------------------------------------------------------------------------
// K4: mega — interleaved roles, g = b%47:
//   g<40 : pae (inline threefry, MFMA with GLOBAL B-fragments, cosine, deg)
//   g<45 : csr_fill -> EPK=(row,e)                            [memory]
//   else : XW1 = x @ c1w (64 nodes/block)                     [memory/LDS]
// B-fragment (nt,cl,quad,kt) = 16 contiguous bytes at dword
// (nt*16+cl)*64 + kt*16 + quad*4 in the [n][k-pair] w2t layout.
// ---------------------------------------------------------------------------
__global__ __launch_bounds__(256, 4) void mega(const float* __restrict__ edgenet,
                                               const float* __restrict__ prm_g,
                                               const uint32_t* __restrict__ w2t,
                                               const float* __restrict__ b2,
                                               const int* __restrict__ rowp,
                                               const int* __restrict__ colp,
                                               float* __restrict__ ew_out,
                                               float* __restrict__ deg,
                                               int* __restrict__ fill,
                                               int2* __restrict__ epk,
                                               const float* __restrict__ x,
                                               const float* __restrict__ c1w,
                                               float* __restrict__ xw1) {
  __shared__ __align__(16) uint8_t smem[33792];
  int b = blockIdx.x;
  int t = threadIdx.x;
  int g = b % 47, u = b / 47;

  if (g < 40) {
    // ---------------- pae role ----------------
    int blk = u * 40 + g;
    if (blk >= PAE_BLOCKS) return;
    float* prm = (float*)smem;                 // 896*4 = 3584 B
    float* b2s = (float*)(smem + 3584);        // 512 B
    int e0 = blk * 32;
    for (int i = t; i < 896; i += 256) prm[i] = prm_g[i];
    if (t < 128) b2s[t] = b2[t];
    __syncthreads();

    int lane = t & 63, w = t >> 6;
    int cl = lane & 15, quad = lane >> 4;
    int quad8 = quad * 8;
    int row = 16 * w + cl;
    int el = row >> 1, s = row & 1;
    int so = s << 7;
    float2 xv = *(const float2*)&edgenet[(size_t)(e0 + el) * 4 + 2 * s];
    uint32_t rowbase = (uint32_t)(e0 + el) * 128u + (s ? 128000000u : 0u);
    const u32x4* w2v = (const u32x4*)w2t;      // fragment base index math below

    f32x4 acc[8];
#pragma unroll
    for (int nt = 0; nt < 8; ++nt) acc[nt] = (f32x4){0.f, 0.f, 0.f, 0.f};

#pragma unroll 1
    for (int kt = 0; kt < 4; ++kt) {
      // issue all 8 B-fragment loads first; threefry below covers latency
      u32x4 bfv[8];
#pragma unroll
      for (int nt = 0; nt < 8; ++nt)
        bfv[nt] = w2v[(nt * 16 + cl) * 16 + kt * 4 + quad];

      int c0 = kt * 32 + quad8;
      uint32_t idxbase = rowbase + (uint32_t)c0;
      float wa[8], wb[8], bb[8], ak[8], bk[8];
      *(float4*)&wa[0] = *(const float4*)&prm[c0];
      *(float4*)&wa[4] = *(const float4*)&prm[c0 + 4];
      *(float4*)&wb[0] = *(const float4*)&prm[128 + c0];
      *(float4*)&wb[4] = *(const float4*)&prm[132 + c0];
      *(float4*)&bb[0] = *(const float4*)&prm[256 + c0];
      *(float4*)&bb[4] = *(const float4*)&prm[260 + c0];
      *(float4*)&ak[0] = *(const float4*)&prm[384 + so + c0];
      *(float4*)&ak[4] = *(const float4*)&prm[388 + so + c0];
      *(float4*)&bk[0] = *(const float4*)&prm[640 + so + c0];
      *(float4*)&bk[4] = *(const float4*)&prm[644 + so + c0];
      uint32_t pk[4];
#pragma unroll
      for (int jp = 0; jp < 4; ++jp) {
        uint32_t uu[2];
#pragma unroll
        for (int q = 0; q < 2; ++q) {
          int j = 2 * jp + q;
          float h = fmaxf(fmaf(xv.y, wb[j], fmaf(xv.x, wa[j], bb[j])), 0.f);
          float hn = fmaf(h, ak[j], bk[j]);
          uint32_t bits = tf_bits_exact<KP.a, KP.b>(idxbase + (uint32_t)j);
          float hd = (bits < KEEP_THR) ? hn : 0.f;
          uu[q] = __float_as_uint(hd) + 0x8000u;
        }
        pk[jp] = __builtin_amdgcn_perm(uu[1], uu[0], 0x07060302u);
      }
      u32x4 pkv = {pk[0], pk[1], pk[2], pk[3]};
      bf16x8 afr = __builtin_bit_cast(bf16x8, pkv);
#pragma unroll
      for (int nt = 0; nt < 8; ++nt) {
        bf16x8 bfr = __builtin_bit_cast(bf16x8, bfv[nt]);
        acc[nt] = __builtin_amdgcn_mfma_f32_16x16x32_bf16(afr, bfr, acc[nt], 0, 0, 0);
      }
    }

    float p11[2] = {0.f, 0.f}, p22[2] = {0.f, 0.f}, p12[2] = {0.f, 0.f};
#pragma unroll
    for (int nt = 0; nt < 8; ++nt) {
      float bv = b2s[nt * 16 + cl];
#pragma unroll
      for (int uq = 0; uq < 2; ++uq) {
        float v1 = acc[nt][2 * uq] + bv;
        float v2 = acc[nt][2 * uq + 1] + bv;
        p11[uq] = fmaf(v1, v1, p11[uq]);
        p22[uq] = fmaf(v2, v2, p22[uq]);
        p12[uq] = fmaf(v1, v2, p12[uq]);
      }
    }
#pragma unroll
    for (int uq = 0; uq < 2; ++uq) {
      float a = p11[uq], bq = p22[uq], d = p12[uq];
      for (int off = 1; off < 16; off <<= 1) {
        a += __shfl_xor(a, off, 64);
        bq += __shfl_xor(bq, off, 64);
        d += __shfl_xor(d, off, 64);
      }
      if (cl == 0) {
        int e = e0 + 8 * w + 2 * quad + uq;
        float n1 = fmaxf(sqrtf(a), 1e-8f);
        float n2 = fmaxf(sqrtf(bq), 1e-8f);
        float ew = (d / (n1 * n2) + 1.f) * 0.5f;
        ew_out[e] = ew;
        atomicAdd(&deg[colp[e]], ew);
      }
    }
  } else if (g < 45) {
    // ---------------- csr_fill role ----------------
    int blk = u * 5 + (g - 40);
    if (blk >= HIST_BLOCKS) return;
    int e = blk * 256 + t;
    if (e < NE) {
      int r = rowp[e];
      int p = atomicAdd(&fill[colp[e]], 1);
      epk[p] = make_int2(r, e);
    }
  } else {
    // ---------------- XW1 = x @ c1w role ----------------
    int blk = u * 2 + (g - 45);
    if (blk >= XW1_BLOCKS) return;
    float* InT = (float*)smem;                 // 64*68*4 = 17408 B
    float* Wl  = (float*)(smem + 17408);       // 64*64*4 = 16384 B
    int v0 = blk * 64;
    for (int i = t; i < 4096; i += 256) {
      Wl[i] = c1w[i];
      int v = i >> 6, k = i & 63;
      int vv = min(v0 + v, NN - 1);
      InT[k * 68 + v] = x[(size_t)vv * 64 + k];
    }
    __syncthreads();
    int tx = t & 15, ty = t >> 4;
    float acc[4][4];
#pragma unroll
    for (int i = 0; i < 4; ++i)
#pragma unroll
      for (int j = 0; j < 4; ++j) acc[i][j] = 0.f;
#pragma unroll 4
    for (int k = 0; k < 64; ++k) {
      float4 av = *(const float4*)&InT[k * 68 + 4 * ty];
      float4 bv = *(const float4*)&Wl[k * 64 + 4 * tx];
      float a4[4] = {av.x, av.y, av.z, av.w};
      float b4[4] = {bv.x, bv.y, bv.z, bv.w};
#pragma unroll
      for (int i = 0; i < 4; ++i)
#pragma unroll
        for (int j = 0; j < 4; ++j) acc[i][j] = fmaf(a4[i], b4[j], acc[i][j]);
    }
    for (int i = 0; i < 4; ++i) {
      int v = v0 + 4 * ty + i;
      if (v < NN)
        *(float4*)&xw1[(size_t)v * 64 + 4 * tx] =
            make_float4(acc[i][0], acc[i][1], acc[i][2], acc[i][3]);
    }
  }
}

// ---------------------------------------------------------------------------
// K5: conv1 gather (on XW1) + fused coefficient compute/writeback.
// EPK in: (row, edge) -> computes cf = rsqrt(deg[r]+1)*ew[e], uses it, and
// lane-0 rewrites EPK[p] = (row, cf) for conv2. One wave per node.
// ---------------------------------------------------------------------------
__global__ __launch_bounds__(256) void conv1g(const int* __restrict__ ptr,
                                              int2* __restrict__ epk,
                                              const float* __restrict__ deg,
                                              const float* __restrict__ ew,
                                              const float* __restrict__ xw,
                                              const float* __restrict__ bias,
                                              uint16_t* __restrict__ h1) {
  int t = threadIdx.x;
  int v = blockIdx.x * 4 + (t >> 6);
  int c = t & 63;
  int p = ptr[v], end = ptr[v + 1];
  float acc = 0.f;
  while (p + 2 <= end) {
    int2 a = epk[p];
    int2 bq = epk[p + 1];
    float cfa = rsqrtf(deg[a.x] + 1.0f) * ew[a.y];
    float cfb = rsqrtf(deg[bq.x] + 1.0f) * ew[bq.y];
    float xa = xw[(size_t)a.x * 64 + c];
    float xb = xw[(size_t)bq.x * 64 + c];
    acc = fmaf(cfa, xa, acc);
    acc = fmaf(cfb, xb, acc);
    if (c == 0) {
      epk[p]     = make_int2(a.x, __float_as_int(cfa));
      epk[p + 1] = make_int2(bq.x, __float_as_int(cfb));
    }
    p += 2;
  }
  if (p < end) {
    int2 a = epk[p];
    float cfa = rsqrtf(deg[a.x] + 1.0f) * ew[a.y];
    acc = fmaf(cfa, xw[(size_t)a.x * 64 + c], acc);
    if (c == 0) epk[p] = make_int2(a.x, __float_as_int(cfa));
  }
  float dv = rsqrtf(deg[v] + 1.0f);
  float val = fmaf(dv, acc, fmaf(dv * dv, xw[(size_t)v * 64 + c], bias[c]));
  h1[(size_t)v * 64 + c] = f2bf(fmaxf(val, 0.f));
}

// ---------------------------------------------------------------------------
// K6: conv2 + full MLP head fused (h1 in bf16), unroll-2 gather, EPK=(r,cf).
// ---------------------------------------------------------------------------
__global__ __launch_bounds__(256) void conv2_head(const int* __restrict__ ptr,
                                                  const int2* __restrict__ epk,
                                                  const float* __restrict__ deg,
                                                  const uint16_t* __restrict__ h1,
                                                  const float* __restrict__ W,
                                                  const float* __restrict__ bias,
                                                  const float* __restrict__ l1w,
                                                  const float* __restrict__ l1b,
                                                  const float* __restrict__ l2w,
                                                  const float* __restrict__ l2b,
                                                  float* __restrict__ out) {
  __shared__ __align__(16) float Ws[4096];     // c2w [k][c']
  __shared__ __align__(16) float T[16 * 68];   // gather out, later reused as M
  __shared__ __align__(16) float H2[16 * 68];
  __shared__ float L1s[64 * 33];               // [k][j]
  __shared__ float L2s[320];                   // [j][f]
  __shared__ float biass[64], l1bs[32], l2bs[16];
  int t = threadIdx.x;
  for (int i = t; i < 4096; i += 256) Ws[i] = W[i];
  for (int i = t; i < 2048; i += 256) {
    int k = i >> 5, j = i & 31;
    L1s[k * 33 + j] = l1w[i];
  }
  for (int i = t; i < 320; i += 256) L2s[i] = l2w[i];
  if (t < 64) biass[t] = bias[t];
  if (t < 32) l1bs[t] = l1b[t];
  if (t < 10) l2bs[t] = l2b[t];
  int w = t >> 6, c = t & 63;
  int v0 = blockIdx.x * 16;
#pragma unroll 1
  for (int i = 0; i < 4; ++i) {
    int n = 4 * w + i;
    int v = v0 + n;
    int p = ptr[v], end = ptr[v + 1];
    float acc = 0.f;
    while (p + 2 <= end) {
      int2 a = epk[p];
      int2 bq = epk[p + 1];
      float xa = bf2f(h1[(size_t)a.x * 64 + c]);
      float xb = bf2f(h1[(size_t)bq.x * 64 + c]);
      acc = fmaf(__int_as_float(a.y), xa, acc);
      acc = fmaf(__int_as_float(bq.y), xb, acc);
      p += 2;
    }
    if (p < end) {
      int2 a = epk[p];
      acc = fmaf(__int_as_float(a.y), bf2f(h1[(size_t)a.x * 64 + c]), acc);
    }
    float dv = rsqrtf(deg[v] + 1.0f);
    T[n * 68 + c] = fmaf(dv, acc, dv * dv * bf2f(h1[(size_t)v * 64 + c]));
  }
  __syncthreads();
  {
    int n = t >> 4, cq = (t & 15) * 4;
    float4 o = *(const float4*)&biass[cq];
#pragma unroll 4
    for (int k = 0; k < 64; ++k) {
      float a = T[n * 68 + k];
      float4 wv = *(const float4*)&Ws[k * 64 + cq];
      o.x = fmaf(a, wv.x, o.x);
      o.y = fmaf(a, wv.y, o.y);
      o.z = fmaf(a, wv.z, o.z);
      o.w = fmaf(a, wv.w, o.w);
    }
    o.x = fmaxf(o.x, 0.f); o.y = fmaxf(o.y, 0.f);
    o.z = fmaxf(o.z, 0.f); o.w = fmaxf(o.w, 0.f);
    __syncthreads();
    *(float4*)&H2[n * 68 + cq] = o;
  }
  __syncthreads();
  {
    int n = t >> 4, j0 = t & 15;
#pragma unroll
    for (int jj = 0; jj < 2; ++jj) {
      int j = j0 + 16 * jj;
      float m = l1bs[j];
#pragma unroll 4
      for (int k = 0; k < 64; ++k) m = fmaf(H2[n * 68 + k], L1s[k * 33 + j], m);
      m = fmaxf(m, 0.f);
      uint32_t idx = (uint32_t)(v0 + n) * 32u + (uint32_t)j;
      bool kp = tf_bits_exact<KH.a, KH.b>(idx) < KEEP_THR;
      T[n * 33 + j] = kp ? m * INV_KEEP : 0.f;
    }
  }
  __syncthreads();
  if (t < 160) {
    int n = t / 10, f = t % 10;
    float s = l2bs[f];
#pragma unroll
    for (int j = 0; j < 32; ++j) s = fmaf(T[n * 33 + j], L2s[j * 10 + f], s);
    out[(size_t)(v0 + n) * 10 + f] = s;
  }
}

// ---------------------------------------------------------------------------
extern "C" void kernel_launch(void* const* d_in, const int* in_sizes, int n_in,
                              void* d_out, int out_size, void* d_ws, size_t ws_size,
                              hipStream_t stream) {
  const float* x       = (const float*)d_in[0];
  const int*   ei      = (const int*)d_in[1];
  const float* edgenet = (const float*)d_in[2];
  const float* pw1     = (const float*)d_in[3];
  const float* pb1     = (const float*)d_in[4];
  const float* pgamma  = (const float*)d_in[5];
  const float* pbeta   = (const float*)d_in[6];
  const float* pw2     = (const float*)d_in[7];
  const float* pb2     = (const float*)d_in[8];
  const float* c1w     = (const float*)d_in[9];
  const float* c1b     = (const float*)d_in[10];
  const float* c2w     = (const float*)d_in[11];
  const float* c2b     = (const float*)d_in[12];
  const float* l1w     = (const float*)d_in[13];
  const float* l1b     = (const float*)d_in[14];
  const float* l2w     = (const float*)d_in[15];
  const float* l2b     = (const float*)d_in[16];
  float* out = (float*)d_out;

  const int* rowp = ei;
  const int* colp = ei + NE;

  // workspace (floats); zero region [bn_sums, DEG, CNT] contiguous
  float* wsf      = (float*)d_ws;
  float* bn_sums  = wsf;                              // 512
  float* DEG      = wsf + 512;                        // NN
  int*   CNT      = (int*)(wsf + 512 + NN);           // NN
  float* EW       = wsf + 512 + 2 * NN;               // NE
  int*   PTR      = (int*)(EW + NE);                  // NN+1
  int*   FILL     = PTR + NN + 1;                     // NN
  int*   BSUM     = FILL + NN;                        // 391 (pad 512)
  uint32_t* W2T   = (uint32_t*)(BSUM + 512);          // 8192
  float* PRM      = (float*)(W2T + 8192);             // 896 (pad 898)
  int2*  EPK      = (int2*)(PRM + 898);               // NE int2 (8 MB)
  float* XW1      = (float*)(EPK + NE);               // NN*64 fp32 (25.6 MB)
  uint16_t* H1    = (uint16_t*)(XW1 + (size_t)NN * 64); // NN*64 bf16 (12.8 MB)

  hipMemsetAsync(bn_sums, 0, (512 + 2 * NN) * sizeof(float), stream);

  phase1<<<BN_BLOCKS + HIST_BLOCKS, 256, 0, stream>>>(edgenet, pw1, pb1, colp,
                                                      bn_sums, CNT);
  csr_scanA<<<391, 256, 0, stream>>>(CNT, PTR, BSUM);
  scanAddPrep<<<408, 512, 0, stream>>>(BSUM, PTR, FILL, bn_sums, pw1, pb1,
                                       pgamma, pbeta, pw2, PRM, W2T);

  mega<<<MEGA_BLOCKS, 256, 0, stream>>>(edgenet, PRM, W2T, pb2, rowp, colp,
                                        EW, DEG, FILL, EPK, x, c1w, XW1);

  conv1g<<<NN / 4, 256, 0, stream>>>(PTR, EPK, DEG, EW, XW1, c1b, H1);
  conv2_head<<<NN / 16, 256, 0, stream>>>(PTR, EPK, DEG, H1, c2w, c2b,
                                          l1w, l1b, l2w, l2b, out);
}

// Round 9
// 1035.946 us; speedup vs baseline: 1.0299x; 1.0299x over previous
//
#include <hip/hip_runtime.h>
#include <stdint.h>

// ---------------------------------------------------------------------------
// Node_GCN: PAE edge weights (MLP+BN+dropout+cosine) -> 2x GCNConv -> MLP head
// R9: (a) csr_coef un-fused from conv1g (R8 fusion added latency-chain loads
// — net zero); (b) mega XW1 role reads c1w from global (L1-hot) instead of
// LDS -> static LDS 17408B -> 6 blocks/CU (launch_bounds(256,6)), recovering
// the VALUBusy lost to B-fragment load stalls at 4 blocks/CU; (c) XW1 stored
// bf16 (halves conv1 gather bytes, L2/L3 footprint 25.6->12.8MB).
// Wall analysis (R5-R8 measured): 256M exact-JAX threefry-20 calls are a
// ~605-650us VALU-issue wall; all pae-independent work rides under it.
// ---------------------------------------------------------------------------

#define NN 100000
#define NE 1000000
#define INV_KEEP (1.0f/0.7f)
// uniform(bits) < 0.7  <=>  bits < 5872026<<9   (0.7f = 0x3F333333 exactly)
#define KEEP_THR 3006477312u

#define BN_BLOCKS   1000
#define HIST_BLOCKS 3907
#define PAE_BLOCKS  31250   // NE/32
#define XW1_BLOCKS  1563    // ceil(NN/64)
#define MEGA_GROUPS 782     // ceil(PAE_BLOCKS/40)
#define MEGA_BLOCKS (MEGA_GROUPS * 47)

typedef short bf16x8 __attribute__((ext_vector_type(8)));
typedef float f32x4  __attribute__((ext_vector_type(4)));
typedef uint32_t u32x4 __attribute__((ext_vector_type(4)));

// ---- threefry2x32 (20 rounds), exact jax/_src/prng.py semantics -----------
__host__ __device__ constexpr uint32_t rotl32c(uint32_t x, int r) {
  return (x << r) | (x >> (32 - r));
}

struct TFK { uint32_t a, b; };
__host__ __device__ constexpr TFK tf_const(uint32_t k0, uint32_t k1,
                                           uint32_t x0, uint32_t x1) {
  uint32_t k2 = k0 ^ k1 ^ 0x1BD11BDAu;
  x0 += k0; x1 += k1;
#define TFC_R(r) { x0 += x1; x1 = rotl32c(x1, (r)); x1 ^= x0; }
  TFC_R(13) TFC_R(15) TFC_R(26) TFC_R(6)   x0 += k1; x1 += k2 + 1u;
  TFC_R(17) TFC_R(29) TFC_R(16) TFC_R(24)  x0 += k2; x1 += k0 + 2u;
  TFC_R(13) TFC_R(15) TFC_R(26) TFC_R(6)   x0 += k0; x1 += k1 + 3u;
  TFC_R(17) TFC_R(29) TFC_R(16) TFC_R(24)  x0 += k1; x1 += k2 + 4u;
  TFC_R(13) TFC_R(15) TFC_R(26) TFC_R(6)   x0 += k2; x1 += k0 + 5u;
#undef TFC_R
  return TFK{x0, x1};
}

// keys from jax.random.split(jax.random.key(42)), partitionable mode
constexpr TFK KP = tf_const(0u, 42u, 0u, 0u);
constexpr TFK KH = tf_const(0u, 42u, 0u, 1u);

// partitionable random bits for element idx: threefry(key,(0,idx)) -> o0^o1
template <uint32_t K0, uint32_t K1>
__device__ __forceinline__ uint32_t tf_bits(uint32_t idx) {
  constexpr uint32_t K2 = K0 ^ K1 ^ 0x1BD11BDAu;
  uint32_t x0 = K0;
  uint32_t x1 = idx + K1;
#define TF_R(r) { x0 += x1; \
    x1 = __builtin_amdgcn_alignbit(x1, x1, 32u - (r)) ^ x0; }
  TF_R(13) TF_R(15) TF_R(26) TF_R(6)   x0 += K1; x1 += K2 + 1u;
  TF_R(17) TF_R(29) TF_R(16) TF_R(24)  x0 += K2; x1 += K0 + 2u;
  TF_R(13) TF_R(15) TF_R(26) TF_R(6)   x0 += K0; x1 += K1 + 3u;
  TF_R(17) TF_R(29) TF_R(16) TF_R(24)  x0 += K1; x1 += K2 + 4u;
  TF_R(13) TF_R(15) TF_R(26) TF_R(6)   x0 += K2; x1 += K0 + 5u;
#undef TF_R
  return x0 ^ x1;
}

__device__ __forceinline__ uint16_t f2bf(float f) {  // RNE
  uint32_t u = __float_as_uint(f);
  return (uint16_t)((u + 0x7FFFu + ((u >> 16) & 1u)) >> 16);
}

__device__ __forceinline__ float bf2f(uint16_t u) {
  return __uint_as_float((uint32_t)u << 16);
}

// ---------------------------------------------------------------------------
// K1: phase1 = bn_stats (blocks 0..999) + csr_hist (1000..4906).
// ---------------------------------------------------------------------------
__global__ __launch_bounds__(256) void phase1(const float* __restrict__ edgenet,
                                              const float* __restrict__ w1,
                                              const float* __restrict__ b1,
                                              const int* __restrict__ colp,
                                              float* __restrict__ sums,
                                              int* __restrict__ cnt) {
  int b = blockIdx.x;
  int t = threadIdx.x;
  if (b < BN_BLOCKS) {
    int c = t & 127, g = t >> 7;
    float wA = w1[c], wB = w1[128 + c], bb = b1[c];
    const float4* ed4 = (const float4*)edgenet;
    int e0 = b * 1000;
    float s0 = 0.f, q0 = 0.f, s1 = 0.f, q1 = 0.f;
#pragma unroll 4
    for (int e = g; e < 1000; e += 2) {
      float4 x = ed4[e0 + e];
      float h = fmaxf(fmaf(x.y, wB, fmaf(x.x, wA, bb)), 0.f);
      s0 += h; q0 = fmaf(h, h, q0);
      h = fmaxf(fmaf(x.w, wB, fmaf(x.z, wA, bb)), 0.f);
      s1 += h; q1 = fmaf(h, h, q1);
    }
    atomicAdd(&sums[c], s0);
    atomicAdd(&sums[256 + c], q0);
    atomicAdd(&sums[128 + c], s1);
    atomicAdd(&sums[384 + c], q1);
  } else {
    int e = (b - BN_BLOCKS) * 256 + t;
    if (e < NE) atomicAdd(&cnt[colp[e]], 1);
  }
}

// ---------------------------------------------------------------------------
// K2: scanA — per-block exclusive scan of cnt into ptr, block totals to bsum.
// ---------------------------------------------------------------------------
__global__ __launch_bounds__(256) void csr_scanA(const int* __restrict__ cnt,
                                                 int* __restrict__ ptr,
                                                 int* __restrict__ bsum) {
  __shared__ int sh[256];
  int t = threadIdx.x;
  int i = blockIdx.x * 256 + t;
  int x = (i < NN) ? cnt[i] : 0;
  sh[t] = x;
  __syncthreads();
  for (int o = 1; o < 256; o <<= 1) {
    int v = (t >= o) ? sh[t - o] : 0;
    __syncthreads();
    sh[t] += v;
    __syncthreads();
  }
  if (i < NN) ptr[i] = sh[t] - x;
  if (t == 255) bsum[blockIdx.x] = sh[255];
}

// ---------------------------------------------------------------------------
// K3: scanAddPrep (512 thr). Blocks 0..390: redundant LDS scan of bsum[391]
// + apply prefix -> final PTR/FILL. Blocks 391..406: w2->bf16 [n][k-pair].
// Block 407: bn_finalize -> PRM.
// PRM (896 floats): [0]wA [128]wB [256]b1 [384]aK[256] [640]bK[256]
// ---------------------------------------------------------------------------
__global__ __launch_bounds__(512) void scanAddPrep(const int* __restrict__ bsum,
                                                   int* __restrict__ ptr,
                                                   int* __restrict__ fill,
                                                   const float* __restrict__ sums,
                                                   const float* __restrict__ w1,
                                                   const float* __restrict__ b1,
                                                   const float* __restrict__ gamma,
                                                   const float* __restrict__ beta,
                                                   const float* __restrict__ w2,
                                                   float* __restrict__ prm,
                                                   uint32_t* __restrict__ w2t) {
  int b = blockIdx.x;
  int t = threadIdx.x;
  if (b < 391) {
    __shared__ int sh[512];
    int x = (t < 391) ? bsum[t] : 0;
    sh[t] = x;
    __syncthreads();
    for (int o = 1; o < 512; o <<= 1) {
      int v = (t >= o) ? sh[t - o] : 0;
      __syncthreads();
      sh[t] += v;
      __syncthreads();
    }
    int excl = (b == 0) ? 0 : sh[b - 1];
    if (t < 256) {
      int i = b * 256 + t;
      if (i < NN) {
        int v = ptr[i] + excl;
        ptr[i] = v;
        fill[i] = v;
        if (i == NN - 1) ptr[NN] = NE;
      }
    }
  } else if (b < 407) {
    int i = (b - 391) * 512 + t;   // < 8192, one uint = 2 bf16 along k
    int n = i >> 6, kp = i & 63;
    float f0 = w2[(2 * kp) * 128 + n];
    float f1 = w2[(2 * kp + 1) * 128 + n];
    w2t[i] = (uint32_t)f2bf(f0) | ((uint32_t)f2bf(f1) << 16);
  } else if (t < 256) {
    int c = t & 127;
    const float invE = 1.0f / (float)NE;
    float mean = sums[t] * invE;
    float var = fmaxf(sums[256 + t] * invE - mean * mean, 0.f);
    float rstd = rsqrtf(var + 1e-5f);
    float a = gamma[c] * rstd;
    prm[384 + t] = a * INV_KEEP;
    prm[640 + t] = (beta[c] - mean * a) * INV_KEEP;
    if (t < 128) { prm[t] = w1[t]; prm[128 + t] = w1[128 + t]; prm[256 + t] = b1[t]; }
  }
}

// ---------------------------------------------------------------------------
// K4: mega — interleaved roles, g = b%47:
//   g<40 : pae (inline threefry, MFMA with GLOBAL B-fragments, cosine, deg)
//   g<45 : csr_fill -> EPK=(row,e)                            [memory]
//   else : XW1 = bf16(x @ c1w), c1w read from global (L1-hot) [memory/LDS]
// B-fragment (nt,cl,quad,kt) = 16 contiguous bytes at dword
// (nt*16+cl)*64 + kt*16 + quad*4 in the [n][k-pair] w2t layout.
// ---------------------------------------------------------------------------
__global__ __launch_bounds__(256, 6) void mega(const float* __restrict__ edgenet,
                                               const float* __restrict__ prm_g,
                                               const uint32_t* __restrict__ w2t,
                                               const float* __restrict__ b2,
                                               const int* __restrict__ rowp,
                                               const int* __restrict__ colp,
                                               float* __restrict__ ew_out,
                                               float* __restrict__ deg,
                                               int* __restrict__ fill,
                                               int2* __restrict__ epk,
                                               const float* __restrict__ x,
                                               const float* __restrict__ c1w,
                                               uint16_t* __restrict__ xw1) {
  __shared__ __align__(16) uint8_t smem[17408];
  int b = blockIdx.x;
  int t = threadIdx.x;
  int g = b % 47, u = b / 47;

  if (g < 40) {
    // ---------------- pae role ----------------
    int blk = u * 40 + g;
    if (blk >= PAE_BLOCKS) return;
    float* prm = (float*)smem;                 // 896*4 = 3584 B
    float* b2s = (float*)(smem + 3584);        // 512 B
    int e0 = blk * 32;
    for (int i = t; i < 896; i += 256) prm[i] = prm_g[i];
    if (t < 128) b2s[t] = b2[t];
    __syncthreads();

    int lane = t & 63, w = t >> 6;
    int cl = lane & 15, quad = lane >> 4;
    int quad8 = quad * 8;
    int row = 16 * w + cl;
    int el = row >> 1, s = row & 1;
    int so = s << 7;
    float2 xv = *(const float2*)&edgenet[(size_t)(e0 + el) * 4 + 2 * s];
    uint32_t rowbase = (uint32_t)(e0 + el) * 128u + (s ? 128000000u : 0u);
    const u32x4* w2v = (const u32x4*)w2t;

    f32x4 acc[8];
#pragma unroll
    for (int nt = 0; nt < 8; ++nt) acc[nt] = (f32x4){0.f, 0.f, 0.f, 0.f};

#pragma unroll 1
    for (int kt = 0; kt < 4; ++kt) {
      // issue all 8 B-fragment loads first; threefry below covers latency
      u32x4 bfv[8];
#pragma unroll
      for (int nt = 0; nt < 8; ++nt)
        bfv[nt] = w2v[(nt * 16 + cl) * 16 + kt * 4 + quad];

      int c0 = kt * 32 + quad8;
      uint32_t idxbase = rowbase + (uint32_t)c0;
      float wa[8], wb[8], bb[8], ak[8], bk[8];
      *(float4*)&wa[0] = *(const float4*)&prm[c0];
      *(float4*)&wa[4] = *(const float4*)&prm[c0 + 4];
      *(float4*)&wb[0] = *(const float4*)&prm[128 + c0];
      *(float4*)&wb[4] = *(const float4*)&prm[132 + c0];
      *(float4*)&bb[0] = *(const float4*)&prm[256 + c0];
      *(float4*)&bb[4] = *(const float4*)&prm[260 + c0];
      *(float4*)&ak[0] = *(const float4*)&prm[384 + so + c0];
      *(float4*)&ak[4] = *(const float4*)&prm[388 + so + c0];
      *(float4*)&bk[0] = *(const float4*)&prm[640 + so + c0];
      *(float4*)&bk[4] = *(const float4*)&prm[644 + so + c0];
      uint32_t pk[4];
#pragma unroll
      for (int jp = 0; jp < 4; ++jp) {
        uint32_t uu[2];
#pragma unroll
        for (int q = 0; q < 2; ++q) {
          int j = 2 * jp + q;
          float h = fmaxf(fmaf(xv.y, wb[j], fmaf(xv.x, wa[j], bb[j])), 0.f);
          float hn = fmaf(h, ak[j], bk[j]);
          uint32_t bits = tf_bits<KP.a, KP.b>(idxbase + (uint32_t)j);
          float hd = (bits < KEEP_THR) ? hn : 0.f;
          uu[q] = __float_as_uint(hd) + 0x8000u;
        }
        pk[jp] = __builtin_amdgcn_perm(uu[1], uu[0], 0x07060302u);
      }
      u32x4 pkv = {pk[0], pk[1], pk[2], pk[3]};
      bf16x8 afr = __builtin_bit_cast(bf16x8, pkv);
#pragma unroll
      for (int nt = 0; nt < 8; ++nt) {
        bf16x8 bfr = __builtin_bit_cast(bf16x8, bfv[nt]);
        acc[nt] = __builtin_amdgcn_mfma_f32_16x16x32_bf16(afr, bfr, acc[nt], 0, 0, 0);
      }
    }

    float p11[2] = {0.f, 0.f}, p22[2] = {0.f, 0.f}, p12[2] = {0.f, 0.f};
#pragma unroll
    for (int nt = 0; nt < 8; ++nt) {
      float bv = b2s[nt * 16 + cl];
#pragma unroll
      for (int uq = 0; uq < 2; ++uq) {
        float v1 = acc[nt][2 * uq] + bv;
        float v2 = acc[nt][2 * uq + 1] + bv;
        p11[uq] = fmaf(v1, v1, p11[uq]);
        p22[uq] = fmaf(v2, v2, p22[uq]);
        p12[uq] = fmaf(v1, v2, p12[uq]);
      }
    }
#pragma unroll
    for (int uq = 0; uq < 2; ++uq) {
      float a = p11[uq], bq = p22[uq], d = p12[uq];
      for (int off = 1; off < 16; off <<= 1) {
        a += __shfl_xor(a, off, 64);
        bq += __shfl_xor(bq, off, 64);
        d += __shfl_xor(d, off, 64);
      }
      if (cl == 0) {
        int e = e0 + 8 * w + 2 * quad + uq;
        float n1 = fmaxf(sqrtf(a), 1e-8f);
        float n2 = fmaxf(sqrtf(bq), 1e-8f);
        float ew = (d / (n1 * n2) + 1.f) * 0.5f;
        ew_out[e] = ew;
        atomicAdd(&deg[colp[e]], ew);
      }
    }
  } else if (g < 45) {
    // ---------------- csr_fill role ----------------
    int blk = u * 5 + (g - 40);
    if (blk >= HIST_BLOCKS) return;
    int e = blk * 256 + t;
    if (e < NE) {
      int r = rowp[e];
      int p = atomicAdd(&fill[colp[e]], 1);
      epk[p] = make_int2(r, e);
    }
  } else {
    // ---------------- XW1 = bf16(x @ c1w) role ----------------
    int blk = u * 2 + (g - 45);
    if (blk >= XW1_BLOCKS) return;
    float* InT = (float*)smem;                 // 64*68*4 = 17408 B
    int v0 = blk * 64;
    for (int i = t; i < 4096; i += 256) {
      int v = i >> 6, k = i & 63;
      int vv = min(v0 + v, NN - 1);
      InT[k * 68 + v] = x[(size_t)vv * 64 + k];
    }
    __syncthreads();
    int tx = t & 15, ty = t >> 4;
    float acc[4][4];
#pragma unroll
    for (int i = 0; i < 4; ++i)
#pragma unroll
      for (int j = 0; j < 4; ++j) acc[i][j] = 0.f;
#pragma unroll 4
    for (int k = 0; k < 64; ++k) {
      float4 av = *(const float4*)&InT[k * 68 + 4 * ty];
      float4 bv = *(const float4*)&c1w[k * 64 + 4 * tx];  // global, L1-hot 16KB
      float a4[4] = {av.x, av.y, av.z, av.w};
      float b4[4] = {bv.x, bv.y, bv.z, bv.w};
#pragma unroll
      for (int i = 0; i < 4; ++i)
#pragma unroll
        for (int j = 0; j < 4; ++j) acc[i][j] = fmaf(a4[i], b4[j], acc[i][j]);
    }
    for (int i = 0; i < 4; ++i) {
      int v = v0 + 4 * ty + i;
      if (v < NN) {
        uint32_t p0 = __builtin_amdgcn_perm(__float_as_uint(acc[i][1]) + 0x8000u,
                                            __float_as_uint(acc[i][0]) + 0x8000u,
                                            0x07060302u);
        uint32_t p1 = __builtin_amdgcn_perm(__float_as_uint(acc[i][3]) + 0x8000u,
                                            __float_as_uint(acc[i][2]) + 0x8000u,
                                            0x07060302u);
        *(uint2*)&xw1[(size_t)v * 64 + 4 * tx] = make_uint2(p0, p1);
      }
    }
  }
}

// ---------------------------------------------------------------------------
// K5: csr_coef: EPK[p]=(r,e) -> (r, dinv_r*ew[e]) in place (deg final).
// ---------------------------------------------------------------------------
__global__ void csr_coef(int2* __restrict__ epk, const float* __restrict__ ew,
                         const float* __restrict__ deg) {
  int p = blockIdx.x * 256 + threadIdx.x;
  if (p < NE) {
    int2 pk = epk[p];
    float cf = rsqrtf(deg[pk.x] + 1.0f) * ew[pk.y];
    epk[p] = make_int2(pk.x, __float_as_int(cf));
  }
}

// ---------------------------------------------------------------------------
// K6: conv1 gather (bf16 XW1): one wave per node, lane = channel, unroll-2.
// H1 (bf16) = relu(dinv*sum cf*XW1[r] + dinv^2*XW1[v] + bias)
// ---------------------------------------------------------------------------
__global__ __launch_bounds__(256) void conv1g(const int* __restrict__ ptr,
                                              const int2* __restrict__ epk,
                                              const float* __restrict__ deg,
                                              const uint16_t* __restrict__ xw,
                                              const float* __restrict__ bias,
                                              uint16_t* __restrict__ h1) {
  int t = threadIdx.x;
  int v = blockIdx.x * 4 + (t >> 6);
  int c = t & 63;
  int p = ptr[v], end = ptr[v + 1];
  float acc = 0.f;
  while (p + 2 <= end) {
    int2 a = epk[p];
    int2 bq = epk[p + 1];
    float xa = bf2f(xw[(size_t)a.x * 64 + c]);
    float xb = bf2f(xw[(size_t)bq.x * 64 + c]);
    acc = fmaf(__int_as_float(a.y), xa, acc);
    acc = fmaf(__int_as_float(bq.y), xb, acc);
    p += 2;
  }
  if (p < end) {
    int2 a = epk[p];
    acc = fmaf(__int_as_float(a.y), bf2f(xw[(size_t)a.x * 64 + c]), acc);
  }
  float dv = rsqrtf(deg[v] + 1.0f);
  float val = fmaf(dv, acc, fmaf(dv * dv, bf2f(xw[(size_t)v * 64 + c]), bias[c]));
  h1[(size_t)v * 64 + c] = f2bf(fmaxf(val, 0.f));
}

// ---------------------------------------------------------------------------
// K7: conv2 + full MLP head fused (h1 in bf16), unroll-2 gather, EPK=(r,cf).
// ---------------------------------------------------------------------------
__global__ __launch_bounds__(256) void conv2_head(const int* __restrict__ ptr,
                                                  const int2* __restrict__ epk,
                                                  const float* __restrict__ deg,
                                                  const uint16_t* __restrict__ h1,
                                                  const float* __restrict__ W,
                                                  const float* __restrict__ bias,
                                                  const float* __restrict__ l1w,
                                                  const float* __restrict__ l1b,
                                                  const float* __restrict__ l2w,
                                                  const float* __restrict__ l2b,
                                                  float* __restrict__ out) {
  __shared__ __align__(16) float Ws[4096];     // c2w [k][c']
  __shared__ __align__(16) float T[16 * 68];   // gather out, later reused as M
  __shared__ __align__(16) float H2[16 * 68];
  __shared__ float L1s[64 * 33];               // [k][j]
  __shared__ float L2s[320];                   // [j][f]
  __shared__ float biass[64], l1bs[32], l2bs[16];
  int t = threadIdx.x;
  for (int i = t; i < 4096; i += 256) Ws[i] = W[i];
  for (int i = t; i < 2048; i += 256) {
    int k = i >> 5, j = i & 31;
    L1s[k * 33 + j] = l1w[i];
  }
  for (int i = t; i < 320; i += 256) L2s[i] = l2w[i];
  if (t < 64) biass[t] = bias[t];
  if (t < 32) l1bs[t] = l1b[t];
  if (t < 10) l2bs[t] = l2b[t];
  int w = t >> 6, c = t & 63;
  int v0 = blockIdx.x * 16;
#pragma unroll 1
  for (int i = 0; i < 4; ++i) {
    int n = 4 * w + i;
    int v = v0 + n;
    int p = ptr[v], end = ptr[v + 1];
    float acc = 0.f;
    while (p + 2 <= end) {
      int2 a = epk[p];
      int2 bq = epk[p + 1];
      float xa = bf2f(h1[(size_t)a.x * 64 + c]);
      float xb = bf2f(h1[(size_t)bq.x * 64 + c]);
      acc = fmaf(__int_as_float(a.y), xa, acc);
      acc = fmaf(__int_as_float(bq.y), xb, acc);
      p += 2;
    }
    if (p < end) {
      int2 a = epk[p];
      acc = fmaf(__int_as_float(a.y), bf2f(h1[(size_t)a.x * 64 + c]), acc);
    }
    float dv = rsqrtf(deg[v] + 1.0f);
    T[n * 68 + c] = fmaf(dv, acc, dv * dv * bf2f(h1[(size_t)v * 64 + c]));
  }
  __syncthreads();
  {
    int n = t >> 4, cq = (t & 15) * 4;
    float4 o = *(const float4*)&biass[cq];
#pragma unroll 4
    for (int k = 0; k < 64; ++k) {
      float a = T[n * 68 + k];
      float4 wv = *(const float4*)&Ws[k * 64 + cq];
      o.x = fmaf(a, wv.x, o.x);
      o.y = fmaf(a, wv.y, o.y);
      o.z = fmaf(a, wv.z, o.z);
      o.w = fmaf(a, wv.w, o.w);
    }
    o.x = fmaxf(o.x, 0.f); o.y = fmaxf(o.y, 0.f);
    o.z = fmaxf(o.z, 0.f); o.w = fmaxf(o.w, 0.f);
    __syncthreads();
    *(float4*)&H2[n * 68 + cq] = o;
  }
  __syncthreads();
  {
    int n = t >> 4, j0 = t & 15;
#pragma unroll
    for (int jj = 0; jj < 2; ++jj) {
      int j = j0 + 16 * jj;
      float m = l1bs[j];
#pragma unroll 4
      for (int k = 0; k < 64; ++k) m = fmaf(H2[n * 68 + k], L1s[k * 33 + j], m);
      m = fmaxf(m, 0.f);
      uint32_t idx = (uint32_t)(v0 + n) * 32u + (uint32_t)j;
      bool kp = tf_bits<KH.a, KH.b>(idx) < KEEP_THR;
      T[n * 33 + j] = kp ? m * INV_KEEP : 0.f;
    }
  }
  __syncthreads();
  if (t < 160) {
    int n = t / 10, f = t % 10;
    float s = l2bs[f];
#pragma unroll
    for (int j = 0; j < 32; ++j) s = fmaf(T[n * 33 + j], L2s[j * 10 + f], s);
    out[(size_t)(v0 + n) * 10 + f] = s;
  }
}

// ---------------------------------------------------------------------------
extern "C" void kernel_launch(void* const* d_in, const int* in_sizes, int n_in,
                              void* d_out, int out_size, void* d_ws, size_t ws_size,
                              hipStream_t stream) {
  const float* x       = (const float*)d_in[0];
  const int*   ei      = (const int*)d_in[1];
  const float* edgenet = (const float*)d_in[2];
  const float* pw1     = (const float*)d_in[3];
  const float* pb1     = (const float*)d_in[4];
  const float* pgamma  = (const float*)d_in[5];
  const float* pbeta   = (const float*)d_in[6];
  const float* pw2     = (const float*)d_in[7];
  const float* pb2     = (const float*)d_in[8];
  const float* c1w     = (const float*)d_in[9];
  const float* c1b     = (const float*)d_in[10];
  const float* c2w     = (const float*)d_in[11];
  const float* c2b     = (const float*)d_in[12];
  const float* l1w     = (const float*)d_in[13];
  const float* l1b     = (const float*)d_in[14];
  const float* l2w     = (const float*)d_in[15];
  const float* l2b     = (const float*)d_in[16];
  float* out = (float*)d_out;

  const int* rowp = ei;
  const int* colp = ei + NE;

  // workspace (floats); zero region [bn_sums, DEG, CNT] contiguous
  float* wsf      = (float*)d_ws;
  float* bn_sums  = wsf;                              // 512
  float* DEG      = wsf + 512;                        // NN
  int*   CNT      = (int*)(wsf + 512 + NN);           // NN
  float* EW       = wsf + 512 + 2 * NN;               // NE
  int*   PTR      = (int*)(EW + NE);                  // NN+1
  int*   FILL     = PTR + NN + 1;                     // NN
  int*   BSUM     = FILL + NN;                        // 391 (pad 512)
  uint32_t* W2T   = (uint32_t*)(BSUM + 512);          // 8192
  float* PRM      = (float*)(W2T + 8192);             // 896 (pad 898)
  int2*  EPK      = (int2*)(PRM + 898);               // NE int2 (8 MB)
  uint16_t* XW1   = (uint16_t*)(EPK + NE);            // NN*64 bf16 (12.8 MB)
  uint16_t* H1    = XW1 + (size_t)NN * 64;            // NN*64 bf16 (12.8 MB)

  hipMemsetAsync(bn_sums, 0, (512 + 2 * NN) * sizeof(float), stream);

  phase1<<<BN_BLOCKS + HIST_BLOCKS, 256, 0, stream>>>(edgenet, pw1, pb1, colp,
                                                      bn_sums, CNT);
  csr_scanA<<<391, 256, 0, stream>>>(CNT, PTR, BSUM);
  scanAddPrep<<<408, 512, 0, stream>>>(BSUM, PTR, FILL, bn_sums, pw1, pb1,
                                       pgamma, pbeta, pw2, PRM, W2T);

  mega<<<MEGA_BLOCKS, 256, 0, stream>>>(edgenet, PRM, W2T, pb2, rowp, colp,
                                        EW, DEG, FILL, EPK, x, c1w, XW1);

  csr_coef<<<(NE + 255) / 256, 256, 0, stream>>>(EPK, EW, DEG);

  conv1g<<<NN / 4, 256, 0, stream>>>(PTR, EPK, DEG, XW1, c1b, H1);
  conv2_head<<<NN / 16, 256, 0, stream>>>(PTR, EPK, DEG, H1, c2w, c2b,
                                          l1w, l1b, l2w, l2b, out);
}

// Round 10
// 976.583 us; speedup vs baseline: 1.0925x; 1.0608x over previous
//
#include <hip/hip_runtime.h>
#include <stdint.h>

// ---------------------------------------------------------------------------
// Node_GCN: PAE edge weights (MLP+BN+dropout+cosine) -> 2x GCNConv -> MLP head
// R10: tail de-latency. (a) conv1g / conv2_head gathers use chunk-4 load
// batching (4 epk + 4 row loads in flight -> 2 exposed latencies per 4 edges);
// (b) conv2_head reads c2w/l1w straight from global (L1-hot) -> LDS 34->10.5KB
// -> 8 blocks/CU; (c) csr_coef 2 edges/thread.
// Wall (R5-R9 measured): 256M exact-JAX threefry-20 calls ≈ 650us VALU-issue
// floor (VALUBusy 94% at both 44% and 74% occupancy); all pae-independent
// work (csr_fill, XW1=x@c1w) rides under it in `mega`.
// ---------------------------------------------------------------------------

#define NN 100000
#define NE 1000000
#define INV_KEEP (1.0f/0.7f)
// uniform(bits) < 0.7  <=>  bits < 5872026<<9   (0.7f = 0x3F333333 exactly)
#define KEEP_THR 3006477312u

#define BN_BLOCKS   1000
#define HIST_BLOCKS 3907
#define PAE_BLOCKS  31250   // NE/32
#define XW1_BLOCKS  1563    // ceil(NN/64)
#define MEGA_GROUPS 782     // ceil(PAE_BLOCKS/40)
#define MEGA_BLOCKS (MEGA_GROUPS * 47)

typedef short bf16x8 __attribute__((ext_vector_type(8)));
typedef float f32x4  __attribute__((ext_vector_type(4)));
typedef uint32_t u32x4 __attribute__((ext_vector_type(4)));

// ---- threefry2x32 (20 rounds), exact jax/_src/prng.py semantics -----------
__host__ __device__ constexpr uint32_t rotl32c(uint32_t x, int r) {
  return (x << r) | (x >> (32 - r));
}

struct TFK { uint32_t a, b; };
__host__ __device__ constexpr TFK tf_const(uint32_t k0, uint32_t k1,
                                           uint32_t x0, uint32_t x1) {
  uint32_t k2 = k0 ^ k1 ^ 0x1BD11BDAu;
  x0 += k0; x1 += k1;
#define TFC_R(r) { x0 += x1; x1 = rotl32c(x1, (r)); x1 ^= x0; }
  TFC_R(13) TFC_R(15) TFC_R(26) TFC_R(6)   x0 += k1; x1 += k2 + 1u;
  TFC_R(17) TFC_R(29) TFC_R(16) TFC_R(24)  x0 += k2; x1 += k0 + 2u;
  TFC_R(13) TFC_R(15) TFC_R(26) TFC_R(6)   x0 += k0; x1 += k1 + 3u;
  TFC_R(17) TFC_R(29) TFC_R(16) TFC_R(24)  x0 += k1; x1 += k2 + 4u;
  TFC_R(13) TFC_R(15) TFC_R(26) TFC_R(6)   x0 += k2; x1 += k0 + 5u;
#undef TFC_R
  return TFK{x0, x1};
}

// keys from jax.random.split(jax.random.key(42)), partitionable mode
constexpr TFK KP = tf_const(0u, 42u, 0u, 0u);
constexpr TFK KH = tf_const(0u, 42u, 0u, 1u);

// partitionable random bits for element idx: threefry(key,(0,idx)) -> o0^o1
template <uint32_t K0, uint32_t K1>
__device__ __forceinline__ uint32_t tf_bits(uint32_t idx) {
  constexpr uint32_t K2 = K0 ^ K1 ^ 0x1BD11BDAu;
  uint32_t x0 = K0;
  uint32_t x1 = idx + K1;
#define TF_R(r) { x0 += x1; \
    x1 = __builtin_amdgcn_alignbit(x1, x1, 32u - (r)) ^ x0; }
  TF_R(13) TF_R(15) TF_R(26) TF_R(6)   x0 += K1; x1 += K2 + 1u;
  TF_R(17) TF_R(29) TF_R(16) TF_R(24)  x0 += K2; x1 += K0 + 2u;
  TF_R(13) TF_R(15) TF_R(26) TF_R(6)   x0 += K0; x1 += K1 + 3u;
  TF_R(17) TF_R(29) TF_R(16) TF_R(24)  x0 += K1; x1 += K2 + 4u;
  TF_R(13) TF_R(15) TF_R(26) TF_R(6)   x0 += K2; x1 += K0 + 5u;
#undef TF_R
  return x0 ^ x1;
}

__device__ __forceinline__ uint16_t f2bf(float f) {  // RNE
  uint32_t u = __float_as_uint(f);
  return (uint16_t)((u + 0x7FFFu + ((u >> 16) & 1u)) >> 16);
}

__device__ __forceinline__ float bf2f(uint16_t u) {
  return __uint_as_float((uint32_t)u << 16);
}

// ---------------------------------------------------------------------------
// K1: phase1 = bn_stats (blocks 0..999) + csr_hist (1000..4906).
// ---------------------------------------------------------------------------
__global__ __launch_bounds__(256) void phase1(const float* __restrict__ edgenet,
                                              const float* __restrict__ w1,
                                              const float* __restrict__ b1,
                                              const int* __restrict__ colp,
                                              float* __restrict__ sums,
                                              int* __restrict__ cnt) {
  int b = blockIdx.x;
  int t = threadIdx.x;
  if (b < BN_BLOCKS) {
    int c = t & 127, g = t >> 7;
    float wA = w1[c], wB = w1[128 + c], bb = b1[c];
    const float4* ed4 = (const float4*)edgenet;
    int e0 = b * 1000;
    float s0 = 0.f, q0 = 0.f, s1 = 0.f, q1 = 0.f;
#pragma unroll 4
    for (int e = g; e < 1000; e += 2) {
      float4 x = ed4[e0 + e];
      float h = fmaxf(fmaf(x.y, wB, fmaf(x.x, wA, bb)), 0.f);
      s0 += h; q0 = fmaf(h, h, q0);
      h = fmaxf(fmaf(x.w, wB, fmaf(x.z, wA, bb)), 0.f);
      s1 += h; q1 = fmaf(h, h, q1);
    }
    atomicAdd(&sums[c], s0);
    atomicAdd(&sums[256 + c], q0);
    atomicAdd(&sums[128 + c], s1);
    atomicAdd(&sums[384 + c], q1);
  } else {
    int e = (b - BN_BLOCKS) * 256 + t;
    if (e < NE) atomicAdd(&cnt[colp[e]], 1);
  }
}

// ---------------------------------------------------------------------------
// K2: scanA — per-block exclusive scan of cnt into ptr, block totals to bsum.
// ---------------------------------------------------------------------------
__global__ __launch_bounds__(256) void csr_scanA(const int* __restrict__ cnt,
                                                 int* __restrict__ ptr,
                                                 int* __restrict__ bsum) {
  __shared__ int sh[256];
  int t = threadIdx.x;
  int i = blockIdx.x * 256 + t;
  int x = (i < NN) ? cnt[i] : 0;
  sh[t] = x;
  __syncthreads();
  for (int o = 1; o < 256; o <<= 1) {
    int v = (t >= o) ? sh[t - o] : 0;
    __syncthreads();
    sh[t] += v;
    __syncthreads();
  }
  if (i < NN) ptr[i] = sh[t] - x;
  if (t == 255) bsum[blockIdx.x] = sh[255];
}

// ---------------------------------------------------------------------------
// K3: scanAddPrep (512 thr). Blocks 0..390: redundant LDS scan of bsum[391]
// + apply prefix -> final PTR/FILL. Blocks 391..406: w2->bf16 [n][k-pair].
// Block 407: bn_finalize -> PRM.
// PRM (896 floats): [0]wA [128]wB [256]b1 [384]aK[256] [640]bK[256]
// ---------------------------------------------------------------------------
__global__ __launch_bounds__(512) void scanAddPrep(const int* __restrict__ bsum,
                                                   int* __restrict__ ptr,
                                                   int* __restrict__ fill,
                                                   const float* __restrict__ sums,
                                                   const float* __restrict__ w1,
                                                   const float* __restrict__ b1,
                                                   const float* __restrict__ gamma,
                                                   const float* __restrict__ beta,
                                                   const float* __restrict__ w2,
                                                   float* __restrict__ prm,
                                                   uint32_t* __restrict__ w2t) {
  int b = blockIdx.x;
  int t = threadIdx.x;
  if (b < 391) {
    __shared__ int sh[512];
    int x = (t < 391) ? bsum[t] : 0;
    sh[t] = x;
    __syncthreads();
    for (int o = 1; o < 512; o <<= 1) {
      int v = (t >= o) ? sh[t - o] : 0;
      __syncthreads();
      sh[t] += v;
      __syncthreads();
    }
    int excl = (b == 0) ? 0 : sh[b - 1];
    if (t < 256) {
      int i = b * 256 + t;
      if (i < NN) {
        int v = ptr[i] + excl;
        ptr[i] = v;
        fill[i] = v;
        if (i == NN - 1) ptr[NN] = NE;
      }
    }
  } else if (b < 407) {
    int i = (b - 391) * 512 + t;   // < 8192, one uint = 2 bf16 along k
    int n = i >> 6, kp = i & 63;
    float f0 = w2[(2 * kp) * 128 + n];
    float f1 = w2[(2 * kp + 1) * 128 + n];
    w2t[i] = (uint32_t)f2bf(f0) | ((uint32_t)f2bf(f1) << 16);
  } else if (t < 256) {
    int c = t & 127;
    const float invE = 1.0f / (float)NE;
    float mean = sums[t] * invE;
    float var = fmaxf(sums[256 + t] * invE - mean * mean, 0.f);
    float rstd = rsqrtf(var + 1e-5f);
    float a = gamma[c] * rstd;
    prm[384 + t] = a * INV_KEEP;
    prm[640 + t] = (beta[c] - mean * a) * INV_KEEP;
    if (t < 128) { prm[t] = w1[t]; prm[128 + t] = w1[128 + t]; prm[256 + t] = b1[t]; }
  }
}

// ---------------------------------------------------------------------------
// K4: mega — interleaved roles, g = b%47:
//   g<40 : pae (inline threefry, MFMA with GLOBAL B-fragments, cosine, deg)
//   g<45 : csr_fill -> EPK=(row,e)                            [memory]
//   else : XW1 = bf16(x @ c1w), c1w read from global (L1-hot) [memory/LDS]
// ---------------------------------------------------------------------------
__global__ __launch_bounds__(256, 6) void mega(const float* __restrict__ edgenet,
                                               const float* __restrict__ prm_g,
                                               const uint32_t* __restrict__ w2t,
                                               const float* __restrict__ b2,
                                               const int* __restrict__ rowp,
                                               const int* __restrict__ colp,
                                               float* __restrict__ ew_out,
                                               float* __restrict__ deg,
                                               int* __restrict__ fill,
                                               int2* __restrict__ epk,
                                               const float* __restrict__ x,
                                               const float* __restrict__ c1w,
                                               uint16_t* __restrict__ xw1) {
  __shared__ __align__(16) uint8_t smem[17408];
  int b = blockIdx.x;
  int t = threadIdx.x;
  int g = b % 47, u = b / 47;

  if (g < 40) {
    // ---------------- pae role ----------------
    int blk = u * 40 + g;
    if (blk >= PAE_BLOCKS) return;
    float* prm = (float*)smem;                 // 896*4 = 3584 B
    float* b2s = (float*)(smem + 3584);        // 512 B
    int e0 = blk * 32;
    for (int i = t; i < 896; i += 256) prm[i] = prm_g[i];
    if (t < 128) b2s[t] = b2[t];
    __syncthreads();

    int lane = t & 63, w = t >> 6;
    int cl = lane & 15, quad = lane >> 4;
    int quad8 = quad * 8;
    int row = 16 * w + cl;
    int el = row >> 1, s = row & 1;
    int so = s << 7;
    float2 xv = *(const float2*)&edgenet[(size_t)(e0 + el) * 4 + 2 * s];
    uint32_t rowbase = (uint32_t)(e0 + el) * 128u + (s ? 128000000u : 0u);
    const u32x4* w2v = (const u32x4*)w2t;

    f32x4 acc[8];
#pragma unroll
    for (int nt = 0; nt < 8; ++nt) acc[nt] = (f32x4){0.f, 0.f, 0.f, 0.f};

#pragma unroll 1
    for (int kt = 0; kt < 4; ++kt) {
      // issue all 8 B-fragment loads first; threefry below covers latency
      u32x4 bfv[8];
#pragma unroll
      for (int nt = 0; nt < 8; ++nt)
        bfv[nt] = w2v[(nt * 16 + cl) * 16 + kt * 4 + quad];

      int c0 = kt * 32 + quad8;
      uint32_t idxbase = rowbase + (uint32_t)c0;
      float wa[8], wb[8], bb[8], ak[8], bk[8];
      *(float4*)&wa[0] = *(const float4*)&prm[c0];
      *(float4*)&wa[4] = *(const float4*)&prm[c0 + 4];
      *(float4*)&wb[0] = *(const float4*)&prm[128 + c0];
      *(float4*)&wb[4] = *(const float4*)&prm[132 + c0];
      *(float4*)&bb[0] = *(const float4*)&prm[256 + c0];
      *(float4*)&bb[4] = *(const float4*)&prm[260 + c0];
      *(float4*)&ak[0] = *(const float4*)&prm[384 + so + c0];
      *(float4*)&ak[4] = *(const float4*)&prm[388 + so + c0];
      *(float4*)&bk[0] = *(const float4*)&prm[640 + so + c0];
      *(float4*)&bk[4] = *(const float4*)&prm[644 + so + c0];
      uint32_t pk[4];
#pragma unroll
      for (int jp = 0; jp < 4; ++jp) {
        uint32_t uu[2];
#pragma unroll
        for (int q = 0; q < 2; ++q) {
          int j = 2 * jp + q;
          float h = fmaxf(fmaf(xv.y, wb[j], fmaf(xv.x, wa[j], bb[j])), 0.f);
          float hn = fmaf(h, ak[j], bk[j]);
          uint32_t bits = tf_bits<KP.a, KP.b>(idxbase + (uint32_t)j);
          float hd = (bits < KEEP_THR) ? hn : 0.f;
          uu[q] = __float_as_uint(hd) + 0x8000u;
        }
        pk[jp] = __builtin_amdgcn_perm(uu[1], uu[0], 0x07060302u);
      }
      u32x4 pkv = {pk[0], pk[1], pk[2], pk[3]};
      bf16x8 afr = __builtin_bit_cast(bf16x8, pkv);
#pragma unroll
      for (int nt = 0; nt < 8; ++nt) {
        bf16x8 bfr = __builtin_bit_cast(bf16x8, bfv[nt]);
        acc[nt] = __builtin_amdgcn_mfma_f32_16x16x32_bf16(afr, bfr, acc[nt], 0, 0, 0);
      }
    }

    float p11[2] = {0.f, 0.f}, p22[2] = {0.f, 0.f}, p12[2] = {0.f, 0.f};
#pragma unroll
    for (int nt = 0; nt < 8; ++nt) {
      float bv = b2s[nt * 16 + cl];
#pragma unroll
      for (int uq = 0; uq < 2; ++uq) {
        float v1 = acc[nt][2 * uq] + bv;
        float v2 = acc[nt][2 * uq + 1] + bv;
        p11[uq] = fmaf(v1, v1, p11[uq]);
        p22[uq] = fmaf(v2, v2, p22[uq]);
        p12[uq] = fmaf(v1, v2, p12[uq]);
      }
    }
#pragma unroll
    for (int uq = 0; uq < 2; ++uq) {
      float a = p11[uq], bq = p22[uq], d = p12[uq];
      for (int off = 1; off < 16; off <<= 1) {
        a += __shfl_xor(a, off, 64);
        bq += __shfl_xor(bq, off, 64);
        d += __shfl_xor(d, off, 64);
      }
      if (cl == 0) {
        int e = e0 + 8 * w + 2 * quad + uq;
        float n1 = fmaxf(sqrtf(a), 1e-8f);
        float n2 = fmaxf(sqrtf(bq), 1e-8f);
        float ew = (d / (n1 * n2) + 1.f) * 0.5f;
        ew_out[e] = ew;
        atomicAdd(&deg[colp[e]], ew);
      }
    }
  } else if (g < 45) {
    // ---------------- csr_fill role ----------------
    int blk = u * 5 + (g - 40);
    if (blk >= HIST_BLOCKS) return;
    int e = blk * 256 + t;
    if (e < NE) {
      int r = rowp[e];
      int p = atomicAdd(&fill[colp[e]], 1);
      epk[p] = make_int2(r, e);
    }
  } else {
    // ---------------- XW1 = bf16(x @ c1w) role ----------------
    int blk = u * 2 + (g - 45);
    if (blk >= XW1_BLOCKS) return;
    float* InT = (float*)smem;                 // 64*68*4 = 17408 B
    int v0 = blk * 64;
    for (int i = t; i < 4096; i += 256) {
      int v = i >> 6, k = i & 63;
      int vv = min(v0 + v, NN - 1);
      InT[k * 68 + v] = x[(size_t)vv * 64 + k];
    }
    __syncthreads();
    int tx = t & 15, ty = t >> 4;
    float acc[4][4];
#pragma unroll
    for (int i = 0; i < 4; ++i)
#pragma unroll
      for (int j = 0; j < 4; ++j) acc[i][j] = 0.f;
#pragma unroll 4
    for (int k = 0; k < 64; ++k) {
      float4 av = *(const float4*)&InT[k * 68 + 4 * ty];
      float4 bv = *(const float4*)&c1w[k * 64 + 4 * tx];  // global, L1-hot 16KB
      float a4[4] = {av.x, av.y, av.z, av.w};
      float b4[4] = {bv.x, bv.y, bv.z, bv.w};
#pragma unroll
      for (int i = 0; i < 4; ++i)
#pragma unroll
        for (int j = 0; j < 4; ++j) acc[i][j] = fmaf(a4[i], b4[j], acc[i][j]);
    }
    for (int i = 0; i < 4; ++i) {
      int v = v0 + 4 * ty + i;
      if (v < NN) {
        uint32_t p0 = __builtin_amdgcn_perm(__float_as_uint(acc[i][1]) + 0x8000u,
                                            __float_as_uint(acc[i][0]) + 0x8000u,
                                            0x07060302u);
        uint32_t p1 = __builtin_amdgcn_perm(__float_as_uint(acc[i][3]) + 0x8000u,
                                            __float_as_uint(acc[i][2]) + 0x8000u,
                                            0x07060302u);
        *(uint2*)&xw1[(size_t)v * 64 + 4 * tx] = make_uint2(p0, p1);
      }
    }
  }
}

// ---------------------------------------------------------------------------
// K5: csr_coef: EPK[p]=(r,e) -> (r, dinv_r*ew[e]) in place, 2 edges/thread.
// ---------------------------------------------------------------------------
__global__ void csr_coef(int2* __restrict__ epk, const float* __restrict__ ew,
                         const float* __restrict__ deg) {
  int p = (blockIdx.x * 256 + threadIdx.x) * 2;
  if (p < NE) {
    int2 a = epk[p];
    int2 b = epk[p + 1];            // NE even -> always valid
    float da = deg[a.x], db = deg[b.x];
    float ea = ew[a.y], eb = ew[b.y];
    epk[p]     = make_int2(a.x, __float_as_int(rsqrtf(da + 1.0f) * ea));
    epk[p + 1] = make_int2(b.x, __float_as_int(rsqrtf(db + 1.0f) * eb));
  }
}

// ---------------------------------------------------------------------------
// K6: conv1 gather (bf16 XW1): one wave per node, lane = channel, chunk-4
// load batching (4 epk + 4 row loads in flight -> 2 exposed latencies / 4).
// H1 (bf16) = relu(dinv*sum cf*XW1[r] + dinv^2*XW1[v] + bias)
// ---------------------------------------------------------------------------
__global__ __launch_bounds__(256) void conv1g(const int* __restrict__ ptr,
                                              const int2* __restrict__ epk,
                                              const float* __restrict__ deg,
                                              const uint16_t* __restrict__ xw,
                                              const float* __restrict__ bias,
                                              uint16_t* __restrict__ h1) {
  int t = threadIdx.x;
  int v = blockIdx.x * 4 + (t >> 6);
  int c = t & 63;
  int p = ptr[v], end = ptr[v + 1];
  float acc = 0.f;
  while (p + 4 <= end) {
    int2 e0 = epk[p], e1 = epk[p + 1], e2 = epk[p + 2], e3 = epk[p + 3];
    float x0 = bf2f(xw[(size_t)e0.x * 64 + c]);
    float x1 = bf2f(xw[(size_t)e1.x * 64 + c]);
    float x2 = bf2f(xw[(size_t)e2.x * 64 + c]);
    float x3 = bf2f(xw[(size_t)e3.x * 64 + c]);
    acc = fmaf(__int_as_float(e0.y), x0, acc);
    acc = fmaf(__int_as_float(e1.y), x1, acc);
    acc = fmaf(__int_as_float(e2.y), x2, acc);
    acc = fmaf(__int_as_float(e3.y), x3, acc);
    p += 4;
  }
  if (p + 2 <= end) {
    int2 e0 = epk[p], e1 = epk[p + 1];
    float x0 = bf2f(xw[(size_t)e0.x * 64 + c]);
    float x1 = bf2f(xw[(size_t)e1.x * 64 + c]);
    acc = fmaf(__int_as_float(e0.y), x0, acc);
    acc = fmaf(__int_as_float(e1.y), x1, acc);
    p += 2;
  }
  if (p < end) {
    int2 a = epk[p];
    acc = fmaf(__int_as_float(a.y), bf2f(xw[(size_t)a.x * 64 + c]), acc);
  }
  float dv = rsqrtf(deg[v] + 1.0f);
  float val = fmaf(dv, acc, fmaf(dv * dv, bf2f(xw[(size_t)v * 64 + c]), bias[c]));
  h1[(size_t)v * 64 + c] = f2bf(fmaxf(val, 0.f));
}

// ---------------------------------------------------------------------------
// K7: conv2 + full MLP head fused. Chunk-4 gather; c2w/l1w read from global
// (L1-hot 16KB/8KB) instead of LDS -> ~10.5KB LDS -> 8 blocks/CU.
// ---------------------------------------------------------------------------
__global__ __launch_bounds__(256) void conv2_head(const int* __restrict__ ptr,
                                                  const int2* __restrict__ epk,
                                                  const float* __restrict__ deg,
                                                  const uint16_t* __restrict__ h1,
                                                  const float* __restrict__ W,
                                                  const float* __restrict__ bias,
                                                  const float* __restrict__ l1w,
                                                  const float* __restrict__ l1b,
                                                  const float* __restrict__ l2w,
                                                  const float* __restrict__ l2b,
                                                  float* __restrict__ out) {
  __shared__ __align__(16) float T[16 * 68];   // gather out, later reused as M
  __shared__ __align__(16) float H2[16 * 68];
  __shared__ float L2s[320];                   // [j][f]
  __shared__ float biass[64], l1bs[32], l2bs[16];
  int t = threadIdx.x;
  for (int i = t; i < 320; i += 256) L2s[i] = l2w[i];
  if (t < 64) biass[t] = bias[t];
  if (t < 32) l1bs[t] = l1b[t];
  if (t < 10) l2bs[t] = l2b[t];
  int w = t >> 6, c = t & 63;
  int v0 = blockIdx.x * 16;
#pragma unroll 1
  for (int i = 0; i < 4; ++i) {
    int n = 4 * w + i;
    int v = v0 + n;
    int p = ptr[v], end = ptr[v + 1];
    float acc = 0.f;
    while (p + 4 <= end) {
      int2 e0 = epk[p], e1 = epk[p + 1], e2 = epk[p + 2], e3 = epk[p + 3];
      float x0 = bf2f(h1[(size_t)e0.x * 64 + c]);
      float x1 = bf2f(h1[(size_t)e1.x * 64 + c]);
      float x2 = bf2f(h1[(size_t)e2.x * 64 + c]);
      float x3 = bf2f(h1[(size_t)e3.x * 64 + c]);
      acc = fmaf(__int_as_float(e0.y), x0, acc);
      acc = fmaf(__int_as_float(e1.y), x1, acc);
      acc = fmaf(__int_as_float(e2.y), x2, acc);
      acc = fmaf(__int_as_float(e3.y), x3, acc);
      p += 4;
    }
    if (p + 2 <= end) {
      int2 e0 = epk[p], e1 = epk[p + 1];
      float x0 = bf2f(h1[(size_t)e0.x * 64 + c]);
      float x1 = bf2f(h1[(size_t)e1.x * 64 + c]);
      acc = fmaf(__int_as_float(e0.y), x0, acc);
      acc = fmaf(__int_as_float(e1.y), x1, acc);
      p += 2;
    }
    if (p < end) {
      int2 a = epk[p];
      acc = fmaf(__int_as_float(a.y), bf2f(h1[(size_t)a.x * 64 + c]), acc);
    }
    float dv = rsqrtf(deg[v] + 1.0f);
    T[n * 68 + c] = fmaf(dv, acc, dv * dv * bf2f(h1[(size_t)v * 64 + c]));
  }
  __syncthreads();
  {
    int n = t >> 4, cq = (t & 15) * 4;
    float4 o = *(const float4*)&biass[cq];
#pragma unroll 4
    for (int k = 0; k < 64; ++k) {
      float a = T[n * 68 + k];
      float4 wv = *(const float4*)&W[k * 64 + cq];   // global, L1-hot 16KB
      o.x = fmaf(a, wv.x, o.x);
      o.y = fmaf(a, wv.y, o.y);
      o.z = fmaf(a, wv.z, o.z);
      o.w = fmaf(a, wv.w, o.w);
    }
    o.x = fmaxf(o.x, 0.f); o.y = fmaxf(o.y, 0.f);
    o.z = fmaxf(o.z, 0.f); o.w = fmaxf(o.w, 0.f);
    __syncthreads();
    *(float4*)&H2[n * 68 + cq] = o;
  }
  __syncthreads();
  {
    int n = t >> 4, j0 = t & 15;
#pragma unroll
    for (int jj = 0; jj < 2; ++jj) {
      int j = j0 + 16 * jj;
      float m = l1bs[j];
#pragma unroll 4
      for (int k = 0; k < 64; ++k) m = fmaf(H2[n * 68 + k], l1w[k * 32 + j], m);
      m = fmaxf(m, 0.f);
      uint32_t idx = (uint32_t)(v0 + n) * 32u + (uint32_t)j;
      bool kp = tf_bits<KH.a, KH.b>(idx) < KEEP_THR;
      T[n * 33 + j] = kp ? m * INV_KEEP : 0.f;
    }
  }
  __syncthreads();
  if (t < 160) {
    int n = t / 10, f = t % 10;
    float s = l2bs[f];
#pragma unroll
    for (int j = 0; j < 32; ++j) s = fmaf(T[n * 33 + j], L2s[j * 10 + f], s);
    out[(size_t)(v0 + n) * 10 + f] = s;
  }
}

// ---------------------------------------------------------------------------
extern "C" void kernel_launch(void* const* d_in, const int* in_sizes, int n_in,
                              void* d_out, int out_size, void* d_ws, size_t ws_size,
                              hipStream_t stream) {
  const float* x       = (const float*)d_in[0];
  const int*   ei      = (const int*)d_in[1];
  const float* edgenet = (const float*)d_in[2];
  const float* pw1     = (const float*)d_in[3];
  const float* pb1     = (const float*)d_in[4];
  const float* pgamma  = (const float*)d_in[5];
  const float* pbeta   = (const float*)d_in[6];
  const float* pw2     = (const float*)d_in[7];
  const float* pb2     = (const float*)d_in[8];
  const float* c1w     = (const float*)d_in[9];
  const float* c1b     = (const float*)d_in[10];
  const float* c2w     = (const float*)d_in[11];
  const float* c2b     = (const float*)d_in[12];
  const float* l1w     = (const float*)d_in[13];
  const float* l1b     = (const float*)d_in[14];
  const float* l2w     = (const float*)d_in[15];
  const float* l2b     = (const float*)d_in[16];
  float* out = (float*)d_out;

  const int* rowp = ei;
  const int* colp = ei + NE;

  // workspace (floats); zero region [bn_sums, DEG, CNT] contiguous
  float* wsf      = (float*)d_ws;
  float* bn_sums  = wsf;                              // 512
  float* DEG      = wsf + 512;                        // NN
  int*   CNT      = (int*)(wsf + 512 + NN);           // NN
  float* EW       = wsf + 512 + 2 * NN;               // NE
  int*   PTR      = (int*)(EW + NE);                  // NN+1
  int*   FILL     = PTR + NN + 1;                     // NN
  int*   BSUM     = FILL + NN;                        // 391 (pad 512)
  uint32_t* W2T   = (uint32_t*)(BSUM + 512);          // 8192
  float* PRM      = (float*)(W2T + 8192);             // 896 (pad 898)
  int2*  EPK      = (int2*)(PRM + 898);               // NE int2 (8 MB)
  uint16_t* XW1   = (uint16_t*)(EPK + NE);            // NN*64 bf16 (12.8 MB)
  uint16_t* H1    = XW1 + (size_t)NN * 64;            // NN*64 bf16 (12.8 MB)

  hipMemsetAsync(bn_sums, 0, (512 + 2 * NN) * sizeof(float), stream);

  phase1<<<BN_BLOCKS + HIST_BLOCKS, 256, 0, stream>>>(edgenet, pw1, pb1, colp,
                                                      bn_sums, CNT);
  csr_scanA<<<391, 256, 0, stream>>>(CNT, PTR, BSUM);
  scanAddPrep<<<408, 512, 0, stream>>>(BSUM, PTR, FILL, bn_sums, pw1, pb1,
                                       pgamma, pbeta, pw2, PRM, W2T);

  mega<<<MEGA_BLOCKS, 256, 0, stream>>>(edgenet, PRM, W2T, pb2, rowp, colp,
                                        EW, DEG, FILL, EPK, x, c1w, XW1);

  csr_coef<<<(NE / 2 + 255) / 256, 256, 0, stream>>>(EPK, EW, DEG);

  conv1g<<<NN / 4, 256, 0, stream>>>(PTR, EPK, DEG, XW1, c1b, H1);
  conv2_head<<<NN / 16, 256, 0, stream>>>(PTR, EPK, DEG, H1, c2w, c2b,
                                          l1w, l1b, l2w, l2b, out);
}

// Round 11
// 944.249 us; speedup vs baseline: 1.1299x; 1.0342x over previous
//
#include <hip/hip_runtime.h>
#include <stdint.h>

// ---------------------------------------------------------------------------
// Node_GCN: PAE edge weights (MLP+BN+dropout+cosine) -> 2x GCNConv -> MLP head
// R11: tail MLP. (a) conv1g / conv2_head gathers: dual-node half-wave layout —
// 32 lanes/node, lane owns a channel PAIR via one uint32 load (2xbf16);
// 2 independent chunk-4 edge streams per wave = 8 loads in flight, half the
// waves. (b) phase1 hist reads colp as int4 (4 edges/thread).
// Wall (R5-R10 measured): 256M exact-JAX threefry-20 calls ≈ 605-650us
// VALU-issue floor, insensitive to occupancy/LDS/B-sourcing; all
// pae-independent work (csr_fill, XW1=x@c1w) rides under it in `mega`.
// ---------------------------------------------------------------------------

#define NN 100000
#define NE 1000000
#define INV_KEEP (1.0f/0.7f)
// uniform(bits) < 0.7  <=>  bits < 5872026<<9   (0.7f = 0x3F333333 exactly)
#define KEEP_THR 3006477312u

#define BN_BLOCKS   1000
#define HIST_BLOCKS 977     // NE / (256*4) rounded up
#define FILL_BLOCKS 3907
#define PAE_BLOCKS  31250   // NE/32
#define XW1_BLOCKS  1563    // ceil(NN/64)
#define MEGA_GROUPS 782     // ceil(PAE_BLOCKS/40)
#define MEGA_BLOCKS (MEGA_GROUPS * 47)

typedef short bf16x8 __attribute__((ext_vector_type(8)));
typedef float f32x4  __attribute__((ext_vector_type(4)));
typedef uint32_t u32x4 __attribute__((ext_vector_type(4)));

// ---- threefry2x32 (20 rounds), exact jax/_src/prng.py semantics -----------
__host__ __device__ constexpr uint32_t rotl32c(uint32_t x, int r) {
  return (x << r) | (x >> (32 - r));
}

struct TFK { uint32_t a, b; };
__host__ __device__ constexpr TFK tf_const(uint32_t k0, uint32_t k1,
                                           uint32_t x0, uint32_t x1) {
  uint32_t k2 = k0 ^ k1 ^ 0x1BD11BDAu;
  x0 += k0; x1 += k1;
#define TFC_R(r) { x0 += x1; x1 = rotl32c(x1, (r)); x1 ^= x0; }
  TFC_R(13) TFC_R(15) TFC_R(26) TFC_R(6)   x0 += k1; x1 += k2 + 1u;
  TFC_R(17) TFC_R(29) TFC_R(16) TFC_R(24)  x0 += k2; x1 += k0 + 2u;
  TFC_R(13) TFC_R(15) TFC_R(26) TFC_R(6)   x0 += k0; x1 += k1 + 3u;
  TFC_R(17) TFC_R(29) TFC_R(16) TFC_R(24)  x0 += k1; x1 += k2 + 4u;
  TFC_R(13) TFC_R(15) TFC_R(26) TFC_R(6)   x0 += k2; x1 += k0 + 5u;
#undef TFC_R
  return TFK{x0, x1};
}

// keys from jax.random.split(jax.random.key(42)), partitionable mode
constexpr TFK KP = tf_const(0u, 42u, 0u, 0u);
constexpr TFK KH = tf_const(0u, 42u, 0u, 1u);

// partitionable random bits for element idx: threefry(key,(0,idx)) -> o0^o1
template <uint32_t K0, uint32_t K1>
__device__ __forceinline__ uint32_t tf_bits(uint32_t idx) {
  constexpr uint32_t K2 = K0 ^ K1 ^ 0x1BD11BDAu;
  uint32_t x0 = K0;
  uint32_t x1 = idx + K1;
#define TF_R(r) { x0 += x1; \
    x1 = __builtin_amdgcn_alignbit(x1, x1, 32u - (r)) ^ x0; }
  TF_R(13) TF_R(15) TF_R(26) TF_R(6)   x0 += K1; x1 += K2 + 1u;
  TF_R(17) TF_R(29) TF_R(16) TF_R(24)  x0 += K2; x1 += K0 + 2u;
  TF_R(13) TF_R(15) TF_R(26) TF_R(6)   x0 += K0; x1 += K1 + 3u;
  TF_R(17) TF_R(29) TF_R(16) TF_R(24)  x0 += K1; x1 += K2 + 4u;
  TF_R(13) TF_R(15) TF_R(26) TF_R(6)   x0 += K2; x1 += K0 + 5u;
#undef TF_R
  return x0 ^ x1;
}

__device__ __forceinline__ uint16_t f2bf(float f) {  // RNE
  uint32_t u = __float_as_uint(f);
  return (uint16_t)((u + 0x7FFFu + ((u >> 16) & 1u)) >> 16);
}

__device__ __forceinline__ float bflo(uint32_t u) {   // low bf16 of packed u32
  return __uint_as_float(u << 16);
}
__device__ __forceinline__ float bfhi(uint32_t u) {   // high bf16
  return __uint_as_float(u & 0xFFFF0000u);
}
__device__ __forceinline__ uint32_t packbf(float a, float b) {  // (lo=a, hi=b)
  return __builtin_amdgcn_perm(__float_as_uint(b) + 0x8000u,
                               __float_as_uint(a) + 0x8000u, 0x07060302u);
}

// ---------------------------------------------------------------------------
// K1: phase1 = bn_stats (blocks 0..999) + csr_hist int4 (1000..1976).
// ---------------------------------------------------------------------------
__global__ __launch_bounds__(256) void phase1(const float* __restrict__ edgenet,
                                              const float* __restrict__ w1,
                                              const float* __restrict__ b1,
                                              const int* __restrict__ colp,
                                              float* __restrict__ sums,
                                              int* __restrict__ cnt) {
  int b = blockIdx.x;
  int t = threadIdx.x;
  if (b < BN_BLOCKS) {
    int c = t & 127, g = t >> 7;
    float wA = w1[c], wB = w1[128 + c], bb = b1[c];
    const float4* ed4 = (const float4*)edgenet;
    int e0 = b * 1000;
    float s0 = 0.f, q0 = 0.f, s1 = 0.f, q1 = 0.f;
#pragma unroll 4
    for (int e = g; e < 1000; e += 2) {
      float4 x = ed4[e0 + e];
      float h = fmaxf(fmaf(x.y, wB, fmaf(x.x, wA, bb)), 0.f);
      s0 += h; q0 = fmaf(h, h, q0);
      h = fmaxf(fmaf(x.w, wB, fmaf(x.z, wA, bb)), 0.f);
      s1 += h; q1 = fmaf(h, h, q1);
    }
    atomicAdd(&sums[c], s0);
    atomicAdd(&sums[256 + c], q0);
    atomicAdd(&sums[128 + c], s1);
    atomicAdd(&sums[384 + c], q1);
  } else {
    int e = ((b - BN_BLOCKS) * 256 + t) * 4;
    if (e < NE) {
      int4 cc = *(const int4*)&colp[e];
      atomicAdd(&cnt[cc.x], 1);
      atomicAdd(&cnt[cc.y], 1);
      atomicAdd(&cnt[cc.z], 1);
      atomicAdd(&cnt[cc.w], 1);
    }
  }
}

// ---------------------------------------------------------------------------
// K2: scanA — per-block exclusive scan of cnt into ptr, block totals to bsum.
// ---------------------------------------------------------------------------
__global__ __launch_bounds__(256) void csr_scanA(const int* __restrict__ cnt,
                                                 int* __restrict__ ptr,
                                                 int* __restrict__ bsum) {
  __shared__ int sh[256];
  int t = threadIdx.x;
  int i = blockIdx.x * 256 + t;
  int x = (i < NN) ? cnt[i] : 0;
  sh[t] = x;
  __syncthreads();
  for (int o = 1; o < 256; o <<= 1) {
    int v = (t >= o) ? sh[t - o] : 0;
    __syncthreads();
    sh[t] += v;
    __syncthreads();
  }
  if (i < NN) ptr[i] = sh[t] - x;
  if (t == 255) bsum[blockIdx.x] = sh[255];
}

// ---------------------------------------------------------------------------
// K3: scanAddPrep (512 thr). Blocks 0..390: redundant LDS scan of bsum[391]
// + apply prefix -> final PTR/FILL. Blocks 391..406: w2->bf16 [n][k-pair].
// Block 407: bn_finalize -> PRM.
// PRM (896 floats): [0]wA [128]wB [256]b1 [384]aK[256] [640]bK[256]
// ---------------------------------------------------------------------------
__global__ __launch_bounds__(512) void scanAddPrep(const int* __restrict__ bsum,
                                                   int* __restrict__ ptr,
                                                   int* __restrict__ fill,
                                                   const float* __restrict__ sums,
                                                   const float* __restrict__ w1,
                                                   const float* __restrict__ b1,
                                                   const float* __restrict__ gamma,
                                                   const float* __restrict__ beta,
                                                   const float* __restrict__ w2,
                                                   float* __restrict__ prm,
                                                   uint32_t* __restrict__ w2t) {
  int b = blockIdx.x;
  int t = threadIdx.x;
  if (b < 391) {
    __shared__ int sh[512];
    int x = (t < 391) ? bsum[t] : 0;
    sh[t] = x;
    __syncthreads();
    for (int o = 1; o < 512; o <<= 1) {
      int v = (t >= o) ? sh[t - o] : 0;
      __syncthreads();
      sh[t] += v;
      __syncthreads();
    }
    int excl = (b == 0) ? 0 : sh[b - 1];
    if (t < 256) {
      int i = b * 256 + t;
      if (i < NN) {
        int v = ptr[i] + excl;
        ptr[i] = v;
        fill[i] = v;
        if (i == NN - 1) ptr[NN] = NE;
      }
    }
  } else if (b < 407) {
    int i = (b - 391) * 512 + t;   // < 8192, one uint = 2 bf16 along k
    int n = i >> 6, kp = i & 63;
    float f0 = w2[(2 * kp) * 128 + n];
    float f1 = w2[(2 * kp + 1) * 128 + n];
    w2t[i] = (uint32_t)f2bf(f0) | ((uint32_t)f2bf(f1) << 16);
  } else if (t < 256) {
    int c = t & 127;
    const float invE = 1.0f / (float)NE;
    float mean = sums[t] * invE;
    float var = fmaxf(sums[256 + t] * invE - mean * mean, 0.f);
    float rstd = rsqrtf(var + 1e-5f);
    float a = gamma[c] * rstd;
    prm[384 + t] = a * INV_KEEP;
    prm[640 + t] = (beta[c] - mean * a) * INV_KEEP;
    if (t < 128) { prm[t] = w1[t]; prm[128 + t] = w1[128 + t]; prm[256 + t] = b1[t]; }
  }
}

// ---------------------------------------------------------------------------
// K4: mega — interleaved roles, g = b%47:
//   g<40 : pae (inline threefry, MFMA with GLOBAL B-fragments, cosine, deg)
//   g<45 : csr_fill -> EPK=(row,e)                            [memory]
//   else : XW1 = bf16(x @ c1w), c1w read from global (L1-hot) [memory/LDS]
// ---------------------------------------------------------------------------
__global__ __launch_bounds__(256, 6) void mega(const float* __restrict__ edgenet,
                                               const float* __restrict__ prm_g,
                                               const uint32_t* __restrict__ w2t,
                                               const float* __restrict__ b2,
                                               const int* __restrict__ rowp,
                                               const int* __restrict__ colp,
                                               float* __restrict__ ew_out,
                                               float* __restrict__ deg,
                                               int* __restrict__ fill,
                                               int2* __restrict__ epk,
                                               const float* __restrict__ x,
                                               const float* __restrict__ c1w,
                                               uint32_t* __restrict__ xw1) {
  __shared__ __align__(16) uint8_t smem[17408];
  int b = blockIdx.x;
  int t = threadIdx.x;
  int g = b % 47, u = b / 47;

  if (g < 40) {
    // ---------------- pae role ----------------
    int blk = u * 40 + g;
    if (blk >= PAE_BLOCKS) return;
    float* prm = (float*)smem;                 // 896*4 = 3584 B
    float* b2s = (float*)(smem + 3584);        // 512 B
    int e0 = blk * 32;
    for (int i = t; i < 896; i += 256) prm[i] = prm_g[i];
    if (t < 128) b2s[t] = b2[t];
    __syncthreads();

    int lane = t & 63, w = t >> 6;
    int cl = lane & 15, quad = lane >> 4;
    int quad8 = quad * 8;
    int row = 16 * w + cl;
    int el = row >> 1, s = row & 1;
    int so = s << 7;
    float2 xv = *(const float2*)&edgenet[(size_t)(e0 + el) * 4 + 2 * s];
    uint32_t rowbase = (uint32_t)(e0 + el) * 128u + (s ? 128000000u : 0u);
    const u32x4* w2v = (const u32x4*)w2t;

    f32x4 acc[8];
#pragma unroll
    for (int nt = 0; nt < 8; ++nt) acc[nt] = (f32x4){0.f, 0.f, 0.f, 0.f};

#pragma unroll 1
    for (int kt = 0; kt < 4; ++kt) {
      // issue all 8 B-fragment loads first; threefry below covers latency
      u32x4 bfv[8];
#pragma unroll
      for (int nt = 0; nt < 8; ++nt)
        bfv[nt] = w2v[(nt * 16 + cl) * 16 + kt * 4 + quad];

      int c0 = kt * 32 + quad8;
      uint32_t idxbase = rowbase + (uint32_t)c0;
      float wa[8], wb[8], bb[8], ak[8], bk[8];
      *(float4*)&wa[0] = *(const float4*)&prm[c0];
      *(float4*)&wa[4] = *(const float4*)&prm[c0 + 4];
      *(float4*)&wb[0] = *(const float4*)&prm[128 + c0];
      *(float4*)&wb[4] = *(const float4*)&prm[132 + c0];
      *(float4*)&bb[0] = *(const float4*)&prm[256 + c0];
      *(float4*)&bb[4] = *(const float4*)&prm[260 + c0];
      *(float4*)&ak[0] = *(const float4*)&prm[384 + so + c0];
      *(float4*)&ak[4] = *(const float4*)&prm[388 + so + c0];
      *(float4*)&bk[0] = *(const float4*)&prm[640 + so + c0];
      *(float4*)&bk[4] = *(const float4*)&prm[644 + so + c0];
      uint32_t pk[4];
#pragma unroll
      for (int jp = 0; jp < 4; ++jp) {
        uint32_t uu[2];
#pragma unroll
        for (int q = 0; q < 2; ++q) {
          int j = 2 * jp + q;
          float h = fmaxf(fmaf(xv.y, wb[j], fmaf(xv.x, wa[j], bb[j])), 0.f);
          float hn = fmaf(h, ak[j], bk[j]);
          uint32_t bits = tf_bits<KP.a, KP.b>(idxbase + (uint32_t)j);
          float hd = (bits < KEEP_THR) ? hn : 0.f;
          uu[q] = __float_as_uint(hd) + 0x8000u;
        }
        pk[jp] = __builtin_amdgcn_perm(uu[1], uu[0], 0x07060302u);
      }
      u32x4 pkv = {pk[0], pk[1], pk[2], pk[3]};
      bf16x8 afr = __builtin_bit_cast(bf16x8, pkv);
#pragma unroll
      for (int nt = 0; nt < 8; ++nt) {
        bf16x8 bfr = __builtin_bit_cast(bf16x8, bfv[nt]);
        acc[nt] = __builtin_amdgcn_mfma_f32_16x16x32_bf16(afr, bfr, acc[nt], 0, 0, 0);
      }
    }

    float p11[2] = {0.f, 0.f}, p22[2] = {0.f, 0.f}, p12[2] = {0.f, 0.f};
#pragma unroll
    for (int nt = 0; nt < 8; ++nt) {
      float bv = b2s[nt * 16 + cl];
#pragma unroll
      for (int uq = 0; uq < 2; ++uq) {
        float v1 = acc[nt][2 * uq] + bv;
        float v2 = acc[nt][2 * uq + 1] + bv;
        p11[uq] = fmaf(v1, v1, p11[uq]);
        p22[uq] = fmaf(v2, v2, p22[uq]);
        p12[uq] = fmaf(v1, v2, p12[uq]);
      }
    }
#pragma unroll
    for (int uq = 0; uq < 2; ++uq) {
      float a = p11[uq], bq = p22[uq], d = p12[uq];
      for (int off = 1; off < 16; off <<= 1) {
        a += __shfl_xor(a, off, 64);
        bq += __shfl_xor(bq, off, 64);
        d += __shfl_xor(d, off, 64);
      }
      if (cl == 0) {
        int e = e0 + 8 * w + 2 * quad + uq;
        float n1 = fmaxf(sqrtf(a), 1e-8f);
        float n2 = fmaxf(sqrtf(bq), 1e-8f);
        float ew = (d / (n1 * n2) + 1.f) * 0.5f;
        ew_out[e] = ew;
        atomicAdd(&deg[colp[e]], ew);
      }
    }
  } else if (g < 45) {
    // ---------------- csr_fill role ----------------
    int blk = u * 5 + (g - 40);
    if (blk >= FILL_BLOCKS) return;
    int e = blk * 256 + t;
    if (e < NE) {
      int r = rowp[e];
      int p = atomicAdd(&fill[colp[e]], 1);
      epk[p] = make_int2(r, e);
    }
  } else {
    // ---------------- XW1 = bf16(x @ c1w) role ----------------
    int blk = u * 2 + (g - 45);
    if (blk >= XW1_BLOCKS) return;
    float* InT = (float*)smem;                 // 64*68*4 = 17408 B
    int v0 = blk * 64;
    for (int i = t; i < 4096; i += 256) {
      int v = i >> 6, k = i & 63;
      int vv = min(v0 + v, NN - 1);
      InT[k * 68 + v] = x[(size_t)vv * 64 + k];
    }
    __syncthreads();
    int tx = t & 15, ty = t >> 4;
    float acc[4][4];
#pragma unroll
    for (int i = 0; i < 4; ++i)
#pragma unroll
      for (int j = 0; j < 4; ++j) acc[i][j] = 0.f;
#pragma unroll 4
    for (int k = 0; k < 64; ++k) {
      float4 av = *(const float4*)&InT[k * 68 + 4 * ty];
      float4 bv = *(const float4*)&c1w[k * 64 + 4 * tx];  // global, L1-hot 16KB
      float a4[4] = {av.x, av.y, av.z, av.w};
      float b4[4] = {bv.x, bv.y, bv.z, bv.w};
#pragma unroll
      for (int i = 0; i < 4; ++i)
#pragma unroll
        for (int j = 0; j < 4; ++j) acc[i][j] = fmaf(a4[i], b4[j], acc[i][j]);
    }
    for (int i = 0; i < 4; ++i) {
      int v = v0 + 4 * ty + i;
      if (v < NN) {
        uint32_t p0 = packbf(acc[i][0], acc[i][1]);
        uint32_t p1 = packbf(acc[i][2], acc[i][3]);
        *(uint2*)&xw1[(size_t)v * 32 + 2 * tx] = make_uint2(p0, p1);
      }
    }
  }
}

// ---------------------------------------------------------------------------
// K5: csr_coef: EPK[p]=(r,e) -> (r, dinv_r*ew[e]) in place, 2 edges/thread.
// ---------------------------------------------------------------------------
__global__ void csr_coef(int2* __restrict__ epk, const float* __restrict__ ew,
                         const float* __restrict__ deg) {
  int p = (blockIdx.x * 256 + threadIdx.x) * 2;
  if (p < NE) {
    int2 a = epk[p];
    int2 b = epk[p + 1];            // NE even -> always valid
    float da = deg[a.x], db = deg[b.x];
    float ea = ew[a.y], eb = ew[b.y];
    epk[p]     = make_int2(a.x, __float_as_int(rsqrtf(da + 1.0f) * ea));
    epk[p + 1] = make_int2(b.x, __float_as_int(rsqrtf(db + 1.0f) * eb));
  }
}

// ---------------------------------------------------------------------------
// K6: conv1 gather, dual-node half-wave: 32 lanes/node, lane owns channel
// pair (2*chp, 2*chp+1) via one uint32 (2xbf16) load. Block = 8 nodes.
// Chunk-4 per node -> 8 loads in flight per wave.
// ---------------------------------------------------------------------------
__global__ __launch_bounds__(256) void conv1g(const int* __restrict__ ptr,
                                              const int2* __restrict__ epk,
                                              const float* __restrict__ deg,
                                              const uint32_t* __restrict__ xw,
                                              const float* __restrict__ bias,
                                              uint32_t* __restrict__ h1) {
  int t = threadIdx.x;
  int v = blockIdx.x * 8 + (t >> 5);
  int chp = t & 31;
  int p = ptr[v], end = ptr[v + 1];
  float a0 = 0.f, a1 = 0.f;
  while (p + 4 <= end) {
    int2 e0 = epk[p], e1 = epk[p + 1], e2 = epk[p + 2], e3 = epk[p + 3];
    uint32_t r0 = xw[(size_t)e0.x * 32 + chp];
    uint32_t r1 = xw[(size_t)e1.x * 32 + chp];
    uint32_t r2 = xw[(size_t)e2.x * 32 + chp];
    uint32_t r3 = xw[(size_t)e3.x * 32 + chp];
    float c0 = __int_as_float(e0.y), c1 = __int_as_float(e1.y);
    float c2 = __int_as_float(e2.y), c3 = __int_as_float(e3.y);
    a0 = fmaf(c0, bflo(r0), a0); a1 = fmaf(c0, bfhi(r0), a1);
    a0 = fmaf(c1, bflo(r1), a0); a1 = fmaf(c1, bfhi(r1), a1);
    a0 = fmaf(c2, bflo(r2), a0); a1 = fmaf(c2, bfhi(r2), a1);
    a0 = fmaf(c3, bflo(r3), a0); a1 = fmaf(c3, bfhi(r3), a1);
    p += 4;
  }
  if (p + 2 <= end) {
    int2 e0 = epk[p], e1 = epk[p + 1];
    uint32_t r0 = xw[(size_t)e0.x * 32 + chp];
    uint32_t r1 = xw[(size_t)e1.x * 32 + chp];
    float c0 = __int_as_float(e0.y), c1 = __int_as_float(e1.y);
    a0 = fmaf(c0, bflo(r0), a0); a1 = fmaf(c0, bfhi(r0), a1);
    a0 = fmaf(c1, bflo(r1), a0); a1 = fmaf(c1, bfhi(r1), a1);
    p += 2;
  }
  if (p < end) {
    int2 e0 = epk[p];
    uint32_t r0 = xw[(size_t)e0.x * 32 + chp];
    float c0 = __int_as_float(e0.y);
    a0 = fmaf(c0, bflo(r0), a0); a1 = fmaf(c0, bfhi(r0), a1);
  }
  float dv = rsqrtf(deg[v] + 1.0f);
  float dv2 = dv * dv;
  uint32_t sf = xw[(size_t)v * 32 + chp];
  float2 bv = *(const float2*)&bias[2 * chp];
  float v0 = fmaf(dv, a0, fmaf(dv2, bflo(sf), bv.x));
  float v1 = fmaf(dv, a1, fmaf(dv2, bfhi(sf), bv.y));
  h1[(size_t)v * 32 + chp] = packbf(fmaxf(v0, 0.f), fmaxf(v1, 0.f));
}

// ---------------------------------------------------------------------------
// K7: conv2 + full MLP head fused. Gather in dual-node half-wave layout
// (wave w handles nodes 4w+2i+h, lane owns channel pair); c2w/l1w from
// global (L1-hot). 16 nodes/block.
// ---------------------------------------------------------------------------
__global__ __launch_bounds__(256) void conv2_head(const int* __restrict__ ptr,
                                                  const int2* __restrict__ epk,
                                                  const float* __restrict__ deg,
                                                  const uint32_t* __restrict__ h1,
                                                  const float* __restrict__ W,
                                                  const float* __restrict__ bias,
                                                  const float* __restrict__ l1w,
                                                  const float* __restrict__ l1b,
                                                  const float* __restrict__ l2w,
                                                  const float* __restrict__ l2b,
                                                  float* __restrict__ out) {
  __shared__ __align__(16) float T[16 * 68];   // gather out, later reused as M
  __shared__ __align__(16) float H2[16 * 68];
  __shared__ float L2s[320];                   // [j][f]
  __shared__ float biass[64], l1bs[32], l2bs[16];
  int t = threadIdx.x;
  for (int i = t; i < 320; i += 256) L2s[i] = l2w[i];
  if (t < 64) biass[t] = bias[t];
  if (t < 32) l1bs[t] = l1b[t];
  if (t < 10) l2bs[t] = l2b[t];
  int w = t >> 6, h = (t >> 5) & 1, chp = t & 31;
  int v0 = blockIdx.x * 16;
#pragma unroll 1
  for (int i = 0; i < 2; ++i) {
    int n = 4 * w + 2 * i + h;
    int v = v0 + n;
    int p = ptr[v], end = ptr[v + 1];
    float a0 = 0.f, a1 = 0.f;
    while (p + 4 <= end) {
      int2 e0 = epk[p], e1 = epk[p + 1], e2 = epk[p + 2], e3 = epk[p + 3];
      uint32_t r0 = h1[(size_t)e0.x * 32 + chp];
      uint32_t r1 = h1[(size_t)e1.x * 32 + chp];
      uint32_t r2 = h1[(size_t)e2.x * 32 + chp];
      uint32_t r3 = h1[(size_t)e3.x * 32 + chp];
      float c0 = __int_as_float(e0.y), c1 = __int_as_float(e1.y);
      float c2 = __int_as_float(e2.y), c3 = __int_as_float(e3.y);
      a0 = fmaf(c0, bflo(r0), a0); a1 = fmaf(c0, bfhi(r0), a1);
      a0 = fmaf(c1, bflo(r1), a0); a1 = fmaf(c1, bfhi(r1), a1);
      a0 = fmaf(c2, bflo(r2), a0); a1 = fmaf(c2, bfhi(r2), a1);
      a0 = fmaf(c3, bflo(r3), a0); a1 = fmaf(c3, bfhi(r3), a1);
      p += 4;
    }
    if (p + 2 <= end) {
      int2 e0 = epk[p], e1 = epk[p + 1];
      uint32_t r0 = h1[(size_t)e0.x * 32 + chp];
      uint32_t r1 = h1[(size_t)e1.x * 32 + chp];
      float c0 = __int_as_float(e0.y), c1 = __int_as_float(e1.y);
      a0 = fmaf(c0, bflo(r0), a0); a1 = fmaf(c0, bfhi(r0), a1);
      a0 = fmaf(c1, bflo(r1), a0); a1 = fmaf(c1, bfhi(r1), a1);
      p += 2;
    }
    if (p < end) {
      int2 e0 = epk[p];
      uint32_t r0 = h1[(size_t)e0.x * 32 + chp];
      float c0 = __int_as_float(e0.y);
      a0 = fmaf(c0, bflo(r0), a0); a1 = fmaf(c0, bfhi(r0), a1);
    }
    float dv = rsqrtf(deg[v] + 1.0f);
    float dv2 = dv * dv;
    uint32_t sf = h1[(size_t)v * 32 + chp];
    *(float2*)&T[n * 68 + 2 * chp] =
        make_float2(fmaf(dv, a0, dv2 * bflo(sf)), fmaf(dv, a1, dv2 * bfhi(sf)));
  }
  __syncthreads();
  {
    int n = t >> 4, cq = (t & 15) * 4;
    float4 o = *(const float4*)&biass[cq];
#pragma unroll 4
    for (int k = 0; k < 64; ++k) {
      float a = T[n * 68 + k];
      float4 wv = *(const float4*)&W[k * 64 + cq];   // global, L1-hot 16KB
      o.x = fmaf(a, wv.x, o.x);
      o.y = fmaf(a, wv.y, o.y);
      o.z = fmaf(a, wv.z, o.z);
      o.w = fmaf(a, wv.w, o.w);
    }
    o.x = fmaxf(o.x, 0.f); o.y = fmaxf(o.y, 0.f);
    o.z = fmaxf(o.z, 0.f); o.w = fmaxf(o.w, 0.f);
    __syncthreads();
    *(float4*)&H2[n * 68 + cq] = o;
  }
  __syncthreads();
  {
    int n = t >> 4, j0 = t & 15;
#pragma unroll
    for (int jj = 0; jj < 2; ++jj) {
      int j = j0 + 16 * jj;
      float m = l1bs[j];
#pragma unroll 4
      for (int k = 0; k < 64; ++k) m = fmaf(H2[n * 68 + k], l1w[k * 32 + j], m);
      m = fmaxf(m, 0.f);
      uint32_t idx = (uint32_t)(v0 + n) * 32u + (uint32_t)j;
      bool kp = tf_bits<KH.a, KH.b>(idx) < KEEP_THR;
      T[n * 33 + j] = kp ? m * INV_KEEP : 0.f;
    }
  }
  __syncthreads();
  if (t < 160) {
    int n = t / 10, f = t % 10;
    float s = l2bs[f];
#pragma unroll
    for (int j = 0; j < 32; ++j) s = fmaf(T[n * 33 + j], L2s[j * 10 + f], s);
    out[(size_t)(v0 + n) * 10 + f] = s;
  }
}

// ---------------------------------------------------------------------------
extern "C" void kernel_launch(void* const* d_in, const int* in_sizes, int n_in,
                              void* d_out, int out_size, void* d_ws, size_t ws_size,
                              hipStream_t stream) {
  const float* x       = (const float*)d_in[0];
  const int*   ei      = (const int*)d_in[1];
  const float* edgenet = (const float*)d_in[2];
  const float* pw1     = (const float*)d_in[3];
  const float* pb1     = (const float*)d_in[4];
  const float* pgamma  = (const float*)d_in[5];
  const float* pbeta   = (const float*)d_in[6];
  const float* pw2     = (const float*)d_in[7];
  const float* pb2     = (const float*)d_in[8];
  const float* c1w     = (const float*)d_in[9];
  const float* c1b     = (const float*)d_in[10];
  const float* c2w     = (const float*)d_in[11];
  const float* c2b     = (const float*)d_in[12];
  const float* l1w     = (const float*)d_in[13];
  const float* l1b     = (const float*)d_in[14];
  const float* l2w     = (const float*)d_in[15];
  const float* l2b     = (const float*)d_in[16];
  float* out = (float*)d_out;

  const int* rowp = ei;
  const int* colp = ei + NE;

  // workspace (floats); zero region [bn_sums, DEG, CNT] contiguous
  float* wsf      = (float*)d_ws;
  float* bn_sums  = wsf;                              // 512
  float* DEG      = wsf + 512;                        // NN
  int*   CNT      = (int*)(wsf + 512 + NN);           // NN
  float* EW       = wsf + 512 + 2 * NN;               // NE
  int*   PTR      = (int*)(EW + NE);                  // NN+1
  int*   FILL     = PTR + NN + 1;                     // NN
  int*   BSUM     = FILL + NN;                        // 391 (pad 512)
  uint32_t* W2T   = (uint32_t*)(BSUM + 512);          // 8192
  float* PRM      = (float*)(W2T + 8192);             // 896 (pad 898)
  int2*  EPK      = (int2*)(PRM + 898);               // NE int2 (8 MB)
  uint32_t* XW1   = (uint32_t*)(EPK + NE);            // NN*32 u32 (12.8 MB)
  uint32_t* H1    = XW1 + (size_t)NN * 32;            // NN*32 u32 (12.8 MB)

  hipMemsetAsync(bn_sums, 0, (512 + 2 * NN) * sizeof(float), stream);

  phase1<<<BN_BLOCKS + HIST_BLOCKS, 256, 0, stream>>>(edgenet, pw1, pb1, colp,
                                                      bn_sums, CNT);
  csr_scanA<<<391, 256, 0, stream>>>(CNT, PTR, BSUM);
  scanAddPrep<<<408, 512, 0, stream>>>(BSUM, PTR, FILL, bn_sums, pw1, pb1,
                                       pgamma, pbeta, pw2, PRM, W2T);

  mega<<<MEGA_BLOCKS, 256, 0, stream>>>(edgenet, PRM, W2T, pb2, rowp, colp,
                                        EW, DEG, FILL, EPK, x, c1w, XW1);

  csr_coef<<<(NE / 2 + 255) / 256, 256, 0, stream>>>(EPK, EW, DEG);

  conv1g<<<NN / 8, 256, 0, stream>>>(PTR, EPK, DEG, XW1, c1b, H1);
  conv2_head<<<NN / 16, 256, 0, stream>>>(PTR, EPK, DEG, H1, c2w, c2b,
                                          l1w, l1b, l2w, l2b, out);
}